// Round 5
// baseline (437.017 us; speedup 1.0000x reference)
//
#include <hip/hip_runtime.h>
#include <hip/hip_bf16.h>
#include <math.h>

// Problem constants (match reference setup_inputs()).
#define N_NODES 20000
#define N_EDGES 320000
#define N_GRAPHS 64
#define SEQ 20
#define SCALAR 16
#define EMB 32
#define HID 128
#define IN_DIM 176         // SCALAR + 5*EMB
#define TOT_EDGES (N_EDGES + N_NODES)  // with self loops
#define CHUNK_SMALL 10000  // fallback node chunk when workspace is tight
#define POOL_SLICES 32     // parallel slices per graph for max-pool

// f16 MFMA types
typedef _Float16 half8v __attribute__((ext_vector_type(8)));
typedef float f32x4 __attribute__((ext_vector_type(4)));
#define LO_SCALE 2048.0f
#define LO_INV (1.0f / 2048.0f)

// Pack-buffer element counts (f16 elems each, hi and lo separately)
#define PB2_ELEMS (16 * 8 * 64 * 8)      // [ks16][ntile8][lane64][j8] = 65536
#define PB1_ELEMS (4 * 6 * 8 * 64 * 8)   // [head4][ks6][ntile8][lane64][j8] = 98304

__device__ inline float readlane_f(float v, int l) {
  return __uint_as_float(__builtin_amdgcn_readlane(__float_as_uint(v), l));
}
__device__ inline int readlane_i(int v, int l) {
  return __builtin_amdgcn_readlane(v, l);
}
__device__ inline float leaky(float e) { return e >= 0.f ? e : 0.2f * e; }
__device__ inline float elu(float v) { return v > 0.f ? v : expf(v) - 1.f; }

// ---------------------------------------------------------------------------
// feats+LN, wave-per-node (4 nodes / 256-thread block, ZERO barriers).
// ---------------------------------------------------------------------------
__global__ __launch_bounds__(256) void feats_ln_kernel(
    const float* __restrict__ xs,
    const int* __restrict__ i0, const int* __restrict__ i1,
    const int* __restrict__ i2, const int* __restrict__ i3,
    const int* __restrict__ i4,
    const float* __restrict__ t0, const float* __restrict__ t1,
    const float* __restrict__ t2, const float* __restrict__ t3,
    const float* __restrict__ t4,
    const float* __restrict__ gamma, const float* __restrict__ beta,
    float* __restrict__ hout) {
  int lane = threadIdx.x & 63;
  int w = threadIdx.x >> 6;
  int n = blockIdx.x * 4 + w;
  if (n >= N_NODES) return;
  __shared__ int sidx[4][100];
  {
    int j = lane;                       // 0..63 -> tabs 0..3
    int tab = j / 20, l = j - tab * 20;
    const int* ip = tab == 0 ? i0 : tab == 1 ? i1 : tab == 2 ? i2 : i3;
    sidx[w][j] = ip[n * SEQ + l];
    if (lane < 36) {
      int j2 = 64 + lane;               // 64..99 -> tabs 3,4
      int tab2 = j2 / 20, l2 = j2 - tab2 * 20;
      const int* ip2 = tab2 == 3 ? i3 : i4;
      sidx[w][j2] = ip2[n * SEQ + l2];
    }
  }
  bool l48 = lane < 48;
  float f0, f1, f2 = 0.f;
  if (lane < SCALAR) {
    f0 = xs[n * SCALAR + lane];
  } else {
    int tt = lane - SCALAR, tab = tt >> 5, d = tt & 31;  // tab 0 or 1
    const float* tp = tab == 0 ? t0 : t1;
    float sum = 0.f, cnt = 0.f;
#pragma unroll
    for (int l = 0; l < SEQ; ++l) {
      int id = sidx[w][tab * 20 + l];
      if (id != 0) { sum += tp[id * EMB + d]; cnt += 1.f; }
    }
    f0 = sum / (cnt + 1e-9f);
  }
  {
    int tt = 48 + lane, tab = tt >> 5, d = tt & 31;      // tab 1,2,3
    const float* tp = tab == 1 ? t1 : tab == 2 ? t2 : t3;
    float sum = 0.f, cnt = 0.f;
#pragma unroll
    for (int l = 0; l < SEQ; ++l) {
      int id = sidx[w][tab * 20 + l];
      if (id != 0) { sum += tp[id * EMB + d]; cnt += 1.f; }
    }
    f1 = sum / (cnt + 1e-9f);
  }
  if (l48) {
    int tt = 112 + lane, tab = tt >> 5, d = tt & 31;     // tab 3 or 4
    const float* tp = tab == 3 ? t3 : t4;
    float sum = 0.f, cnt = 0.f;
#pragma unroll
    for (int l = 0; l < SEQ; ++l) {
      int id = sidx[w][tab * 20 + l];
      if (id != 0) { sum += tp[id * EMB + d]; cnt += 1.f; }
    }
    f2 = sum / (cnt + 1e-9f);
  }
  float s = f0 + f1 + f2;  // f2==0 for lane>=48
  for (int off = 1; off < 64; off <<= 1) s += __shfl_xor(s, off);
  float mu = s / (float)IN_DIM;
  float v = (f0 - mu) * (f0 - mu) + (f1 - mu) * (f1 - mu) +
            (l48 ? (f2 - mu) * (f2 - mu) : 0.f);
  for (int off = 1; off < 64; off <<= 1) v += __shfl_xor(v, off);
  float rstd = 1.0f / sqrtf(v / (float)IN_DIM + 1e-5f);
  float* hr = hout + (size_t)n * IN_DIM;
  hr[lane] = (f0 - mu) * rstd * gamma[lane] + beta[lane];
  hr[64 + lane] = (f1 - mu) * rstd * gamma[64 + lane] + beta[64 + lane];
  if (l48) hr[128 + lane] = (f2 - mu) * rstd * gamma[128 + lane] + beta[128 + lane];
}

// ---------------------------------------------------------------------------
// CSR build.
// ---------------------------------------------------------------------------
__global__ void count_kernel(const int* __restrict__ edge_index,
                             int* __restrict__ cnt, int E, int N) {
  int i = blockIdx.x * blockDim.x + threadIdx.x;
  if (i < E) {
    atomicAdd(&cnt[edge_index[E + i]], 1);
  } else if (i < E + N) {
    atomicAdd(&cnt[i - E], 1);  // self loop dst = node
  }
}

__global__ __launch_bounds__(256) void prefix_kernel(const int* __restrict__ cnt,
                                                     int* __restrict__ indptr,
                                                     int n, int total) {
  __shared__ int ssum[256];
  int t = threadIdx.x;
  int per = (n + 255) / 256;
  int beg = t * per, end = min(beg + per, n);
  int s = 0;
  for (int i = beg; i < end; ++i) s += cnt[i];
  ssum[t] = s;
  __syncthreads();
  if (t == 0) {
    int run = 0;
    for (int i = 0; i < 256; ++i) { int v = ssum[i]; ssum[i] = run; run += v; }
  }
  __syncthreads();
  int run = ssum[t];
  for (int i = beg; i < end; ++i) { indptr[i] = run; run += cnt[i]; }
  if (t == 0) indptr[n] = total;
}

__global__ void scatter_kernel(const int* __restrict__ edge_index,
                               const int* __restrict__ indptr,
                               int* __restrict__ cursor,
                               int* __restrict__ srcs, int E, int N) {
  int i = blockIdx.x * blockDim.x + threadIdx.x;
  int s, d;
  if (i < E) { s = edge_index[i]; d = edge_index[E + i]; }
  else if (i < E + N) { s = i - E; d = s; }
  else return;
  int pos = indptr[d] + atomicAdd(&cursor[d], 1);
  srcs[pos] = s;
}

// ---------------------------------------------------------------------------
// Pack W2 [512,128] fp32 -> f16 hi/lo fragments for mfma_f32_16x16x32_f16.
// Layout: [ks(16)][ntile(8)][lane(64)][j(8)]; elem = W2[ks*32+(l>>4)*8+j][nt*16+(l&15)].
// lo pre-scaled by 2048 to stay in f16 normal range.
// ---------------------------------------------------------------------------
__global__ __launch_bounds__(256) void pack_w2_kernel(
    const float* __restrict__ W2, _Float16* __restrict__ PBh,
    _Float16* __restrict__ PBl) {
  int t = blockIdx.x * 256 + threadIdx.x;  // 8192 threads exactly
  int lane = t & 63, wi = t >> 6;          // wi = ks*8 + ntile
  int r = lane & 15, g = lane >> 4;
  int ks = wi >> 3, ntile = wi & 7;
  int col = ntile * 16 + r;
  size_t o = ((size_t)wi * 64 + lane) * 8;
#pragma unroll
  for (int j = 0; j < 8; ++j) {
    int k = ks * 32 + g * 8 + j;
    float v = W2[(size_t)k * 128 + col];
    _Float16 h = (_Float16)v;
    PBh[o + j] = h;
    PBl[o + j] = (_Float16)((v - (float)h) * LO_SCALE);
  }
}

// ---------------------------------------------------------------------------
// Pack W1 [176,512] fp32 -> per-head f16 hi/lo fragments, K zero-padded to 192.
// Layout: [hh(4)][ks(6)][ntile(8)][lane(64)][j(8)];
// elem = W1[k][hh*128 + ntile*16 + (l&15)], k = ks*32+(l>>4)*8+j, 0 if k>=176.
// ---------------------------------------------------------------------------
__global__ __launch_bounds__(256) void pack_w1_kernel(
    const float* __restrict__ W1, _Float16* __restrict__ PBh,
    _Float16* __restrict__ PBl) {
  int t = blockIdx.x * 256 + threadIdx.x;  // 12288 threads exactly
  int lane = t & 63, wi = t >> 6;          // wi = (hh*6+ks)*8 + ntile
  int r = lane & 15, g = lane >> 4;
  int ntile = wi & 7, rem = wi >> 3;
  int ks = rem % 6, hh = rem / 6;
  int col = hh * 128 + ntile * 16 + r;
  size_t o = ((size_t)wi * 64 + lane) * 8;
#pragma unroll
  for (int j = 0; j < 8; ++j) {
    int k = ks * 32 + g * 8 + j;
    float v = (k < IN_DIM) ? W1[(size_t)k * 512 + col] : 0.f;
    _Float16 h = (_Float16)v;
    PBh[o + j] = h;
    PBl[o + j] = (_Float16)((v - (float)h) * LO_SCALE);
  }
}

// ---------------------------------------------------------------------------
// GEMM1: hw = h @ W1 (PRE-activation, pre-aggregation — the algebraic
// restructure: GEMM first, aggregate after; aggh never materialized).
// f16 hi/lo MFMA 3-product emulation, in-register split (round-3 style; the
// pre-split variant inflated WRITE_SIZE 40->72MB via 2B RMW stores).
// Wave = 32 rows x 64 cols of one head. K padded 192, tail k-offset clamped.
// Fused epilogue: layer-1 att logits a1s/a1d[row][head] += v*att (16-lane
// shfl reduce + atomicAdd into pre-zeroed buffers) — replaces att1h+wasd.
// ---------------------------------------------------------------------------
__global__ __launch_bounds__(256) void gemm1_mfma_kernel(
    const float* __restrict__ h, const half8v* __restrict__ PBh,
    const half8v* __restrict__ PBl, const float* __restrict__ att_s,
    const float* __restrict__ att_d, float* __restrict__ hw,
    float* __restrict__ a_s, float* __restrict__ a_d, int M) {
  int lane = threadIdx.x & 63;
  int wid = (blockIdx.x * 256 + threadIdx.x) >> 6;
  int colhalf = wid & 1;
  int hh = (wid >> 1) & 3;
  int rg = wid >> 3;
  int rows0 = rg * 32;
  if (rows0 >= M) return;
  int r = lane & 15, g = lane >> 4;
  f32x4 acc[2][4] = {};
  f32x4 accm[2][4] = {};
  const float* a0 = h + (size_t)(rows0 + r) * IN_DIM;
  const float* a1 = h + (size_t)(rows0 + 16 + r) * IN_DIM;
#pragma unroll 2
  for (int ks = 0; ks < 6; ++ks) {
    int kg = ks * 32 + g * 8;
    int koff = (kg + 8 <= IN_DIM) ? kg : 0;  // clamp tail in-row (B zeros kill it)
    half8v ah[2], al[2];
#pragma unroll
    for (int mt = 0; mt < 2; ++mt) {
      const float* ap = (mt ? a1 : a0) + koff;
      float av[8];
      *(float4*)&av[0] = *(const float4*)(ap);
      *(float4*)&av[4] = *(const float4*)(ap + 4);
#pragma unroll
      for (int j = 0; j < 8; ++j) {
        _Float16 hv = (_Float16)av[j];
        ah[mt][j] = hv;
        al[mt][j] = (_Float16)((av[j] - (float)hv) * LO_SCALE);
      }
    }
    const half8v* bh = PBh + (size_t)(((hh * 6 + ks) * 8 + colhalf * 4) * 64) + lane;
    const half8v* bl = PBl + (size_t)(((hh * 6 + ks) * 8 + colhalf * 4) * 64) + lane;
#pragma unroll
    for (int nt = 0; nt < 4; ++nt) {
      half8v bhv = bh[nt * 64], blv = bl[nt * 64];
#pragma unroll
      for (int mt = 0; mt < 2; ++mt) {
        accm[mt][nt] = __builtin_amdgcn_mfma_f32_16x16x32_f16(al[mt], bhv, accm[mt][nt], 0, 0, 0);
        accm[mt][nt] = __builtin_amdgcn_mfma_f32_16x16x32_f16(ah[mt], blv, accm[mt][nt], 0, 0, 0);
        acc[mt][nt]  = __builtin_amdgcn_mfma_f32_16x16x32_f16(ah[mt], bhv, acc[mt][nt], 0, 0, 0);
      }
    }
  }
  float ps[2][4] = {}, pd[2][4] = {};
#pragma unroll
  for (int nt = 0; nt < 4; ++nt) {
    int col = hh * 128 + colhalf * 64 + nt * 16 + r;
    float as_ = att_s[col], ad_ = att_d[col];
#pragma unroll
    for (int mt = 0; mt < 2; ++mt) {
#pragma unroll
      for (int i = 0; i < 4; ++i) {
        float v = acc[mt][nt][i] + accm[mt][nt][i] * LO_INV;
        int row = rows0 + mt * 16 + g * 4 + i;
        if (row < M) hw[(size_t)row * 512 + col] = v;   // pre-ELU xw
        ps[mt][i] += v * as_;
        pd[mt][i] += v * ad_;
      }
    }
  }
#pragma unroll
  for (int mt = 0; mt < 2; ++mt) {
#pragma unroll
    for (int i = 0; i < 4; ++i) {
      for (int off = 1; off < 16; off <<= 1) {
        ps[mt][i] += __shfl_xor(ps[mt][i], off);
        pd[mt][i] += __shfl_xor(pd[mt][i], off);
      }
      int row = rows0 + mt * 16 + g * 4 + i;
      if (r == 0 && row < M) {
        atomicAdd(&a_s[row * 4 + hh], ps[mt][i]);
        atomicAdd(&a_d[row * 4 + hh], pd[mt][i]);
      }
    }
  }
}

// ---------------------------------------------------------------------------
// Layer-1 aggregate over hw rows (512 cols). Wave-per-node, zero barriers.
// Lane owns 8 cols [lane*8, lane*8+8) -> single head hd = lane>>4.
// Softmax per head identical to the old agg1h; per edge: broadcast 4 alphas
// via readlane, per-lane select by head, 2x float4 coalesced row loads.
// Epilogue applies bias + ELU -> out1 (chunked).
// ---------------------------------------------------------------------------
__global__ __launch_bounds__(256) void agg1_kernel(
    const float* __restrict__ hw, const float* __restrict__ a_src,
    const float* __restrict__ a_dst, const int* __restrict__ indptr,
    const int* __restrict__ srcs, const float* __restrict__ bias,
    float* __restrict__ out1, int n0, int nM) {
  int lane = threadIdx.x & 63;
  int ln = blockIdx.x * 4 + (threadIdx.x >> 6);
  if (ln >= nM) return;
  int n = n0 + ln;
  int beg = indptr[n], end = indptr[n + 1];
  int deg = end - beg;
  float4 ad = *(const float4*)&a_dst[n * 4];
  int hd = lane >> 4;
  float4 acc0 = make_float4(0.f, 0.f, 0.f, 0.f);
  float4 acc1 = make_float4(0.f, 0.f, 0.f, 0.f);

  auto body = [&](int s, float a) {
    const float* rp = hw + (size_t)s * 512 + lane * 8;
    float4 v0 = *(const float4*)rp;
    float4 v1 = *(const float4*)(rp + 4);
    acc0.x += a * v0.x; acc0.y += a * v0.y; acc0.z += a * v0.z; acc0.w += a * v0.w;
    acc1.x += a * v1.x; acc1.y += a * v1.y; acc1.z += a * v1.z; acc1.w += a * v1.w;
  };
  auto pick = [&](float q0, float q1, float q2, float q3) {
    return hd == 0 ? q0 : hd == 1 ? q1 : hd == 2 ? q2 : q3;
  };

  if (deg <= 64) {
    int j = beg + lane;
    int s = 0;
    float e0 = -INFINITY, e1 = -INFINITY, e2 = -INFINITY, e3 = -INFINITY;
    if (j < end) {
      s = srcs[j];
      float4 as = *(const float4*)&a_src[s * 4];
      e0 = leaky(as.x + ad.x); e1 = leaky(as.y + ad.y);
      e2 = leaky(as.z + ad.z); e3 = leaky(as.w + ad.w);
    }
    float m0 = e0, m1 = e1, m2 = e2, m3 = e3;
    for (int off = 1; off < 64; off <<= 1) {
      m0 = fmaxf(m0, __shfl_xor(m0, off)); m1 = fmaxf(m1, __shfl_xor(m1, off));
      m2 = fmaxf(m2, __shfl_xor(m2, off)); m3 = fmaxf(m3, __shfl_xor(m3, off));
    }
    float x0 = (j < end) ? expf(e0 - m0) : 0.f;
    float x1 = (j < end) ? expf(e1 - m1) : 0.f;
    float x2 = (j < end) ? expf(e2 - m2) : 0.f;
    float x3 = (j < end) ? expf(e3 - m3) : 0.f;
    float d0 = x0, d1 = x1, d2 = x2, d3 = x3;
    for (int off = 1; off < 64; off <<= 1) {
      d0 += __shfl_xor(d0, off); d1 += __shfl_xor(d1, off);
      d2 += __shfl_xor(d2, off); d3 += __shfl_xor(d3, off);
    }
    float al0 = x0 / (d0 + 1e-16f), al1 = x1 / (d1 + 1e-16f);
    float al2 = x2 / (d2 + 1e-16f), al3 = x3 / (d3 + 1e-16f);
    int jj = 0;
    for (; jj + 2 <= deg; jj += 2) {
      int sa = readlane_i(s, jj), sb = readlane_i(s, jj + 1);
      float aa = pick(readlane_f(al0, jj), readlane_f(al1, jj),
                      readlane_f(al2, jj), readlane_f(al3, jj));
      float ab = pick(readlane_f(al0, jj + 1), readlane_f(al1, jj + 1),
                      readlane_f(al2, jj + 1), readlane_f(al3, jj + 1));
      body(sa, aa);
      body(sb, ab);
    }
    if (jj < deg) {
      int sa = readlane_i(s, jj);
      float aa = pick(readlane_f(al0, jj), readlane_f(al1, jj),
                      readlane_f(al2, jj), readlane_f(al3, jj));
      body(sa, aa);
    }
  } else {
    float m0 = -INFINITY, m1 = -INFINITY, m2 = -INFINITY, m3 = -INFINITY;
    for (int j0 = beg; j0 < end; j0 += 64) {
      int j = j0 + lane;
      if (j < end) {
        int s = srcs[j];
        float4 as = *(const float4*)&a_src[s * 4];
        m0 = fmaxf(m0, leaky(as.x + ad.x)); m1 = fmaxf(m1, leaky(as.y + ad.y));
        m2 = fmaxf(m2, leaky(as.z + ad.z)); m3 = fmaxf(m3, leaky(as.w + ad.w));
      }
    }
    for (int off = 1; off < 64; off <<= 1) {
      m0 = fmaxf(m0, __shfl_xor(m0, off)); m1 = fmaxf(m1, __shfl_xor(m1, off));
      m2 = fmaxf(m2, __shfl_xor(m2, off)); m3 = fmaxf(m3, __shfl_xor(m3, off));
    }
    float d0 = 0.f, d1 = 0.f, d2 = 0.f, d3 = 0.f;
    for (int j0 = beg; j0 < end; j0 += 64) {
      int j = j0 + lane;
      if (j < end) {
        int s = srcs[j];
        float4 as = *(const float4*)&a_src[s * 4];
        d0 += expf(leaky(as.x + ad.x) - m0); d1 += expf(leaky(as.y + ad.y) - m1);
        d2 += expf(leaky(as.z + ad.z) - m2); d3 += expf(leaky(as.w + ad.w) - m3);
      }
    }
    for (int off = 1; off < 64; off <<= 1) {
      d0 += __shfl_xor(d0, off); d1 += __shfl_xor(d1, off);
      d2 += __shfl_xor(d2, off); d3 += __shfl_xor(d3, off);
    }
    float r0 = 1.f / (d0 + 1e-16f), r1 = 1.f / (d1 + 1e-16f);
    float r2 = 1.f / (d2 + 1e-16f), r3 = 1.f / (d3 + 1e-16f);
    for (int j0 = beg; j0 < end; j0 += 64) {
      int jn = min(64, end - j0);
      int j = j0 + lane;
      int s = 0;
      float al0 = 0.f, al1 = 0.f, al2 = 0.f, al3 = 0.f;
      if (j < end) {
        s = srcs[j];
        float4 as = *(const float4*)&a_src[s * 4];
        al0 = expf(leaky(as.x + ad.x) - m0) * r0;
        al1 = expf(leaky(as.y + ad.y) - m1) * r1;
        al2 = expf(leaky(as.z + ad.z) - m2) * r2;
        al3 = expf(leaky(as.w + ad.w) - m3) * r3;
      }
      for (int jj = 0; jj < jn; ++jj) {
        int sa = readlane_i(s, jj);
        float aa = pick(readlane_f(al0, jj), readlane_f(al1, jj),
                        readlane_f(al2, jj), readlane_f(al3, jj));
        body(sa, aa);
      }
    }
  }

  const float* bp = bias + lane * 8;
  float4 b0 = *(const float4*)bp;
  float4 b1v = *(const float4*)(bp + 4);
  float4 o0, o1;
  o0.x = elu(acc0.x + b0.x); o0.y = elu(acc0.y + b0.y);
  o0.z = elu(acc0.z + b0.z); o0.w = elu(acc0.w + b0.w);
  o1.x = elu(acc1.x + b1v.x); o1.y = elu(acc1.y + b1v.y);
  o1.z = elu(acc1.z + b1v.z); o1.w = elu(acc1.w + b1v.w);
  size_t ob = (size_t)ln * 512 + lane * 8;
  *(float4*)&out1[ob] = o0;
  *(float4*)&out1[ob + 4] = o1;
}

// ---------------------------------------------------------------------------
// GEMM2 (out1@W2) via f16 hi/lo MFMA + fused layer-2 att logits.
// Round-3 structure (f32 A, in-register hi/lo split). Chunked: A is the
// chunk-local out1 buffer; outputs go to absolute rows n0+row.
// ---------------------------------------------------------------------------
__global__ __launch_bounds__(256) void gemm2att_mfma_kernel(
    const float* __restrict__ A, const half8v* __restrict__ PBh,
    const half8v* __restrict__ PBl, const float* __restrict__ att_s,
    const float* __restrict__ att_d, float* __restrict__ C,
    float* __restrict__ a_s, float* __restrict__ a_d, int nM, int n0) {
  int lane = threadIdx.x & 63;
  int wid = (blockIdx.x * 256 + threadIdx.x) >> 6;
  int colhalf = wid & 1;
  int rg = wid >> 1;
  int row0 = rg * 16;
  if (row0 >= nM) return;
  int r = lane & 15, g = lane >> 4;
  const float* arow = A + (size_t)(row0 + r) * 512 + g * 8;
  f32x4 acc[4] = {};
  f32x4 accm[4] = {};
#pragma unroll 2
  for (int ks = 0; ks < 16; ++ks) {
    float av[8];
    *(float4*)&av[0] = *(const float4*)(arow + ks * 32);
    *(float4*)&av[4] = *(const float4*)(arow + ks * 32 + 4);
    half8v ah, al;
#pragma unroll
    for (int j = 0; j < 8; ++j) {
      _Float16 hv = (_Float16)av[j];
      ah[j] = hv;
      al[j] = (_Float16)((av[j] - (float)hv) * LO_SCALE);
    }
    const half8v* bh = PBh + (size_t)((ks * 8 + colhalf * 4) * 64) + lane;
    const half8v* bl = PBl + (size_t)((ks * 8 + colhalf * 4) * 64) + lane;
#pragma unroll
    for (int nt = 0; nt < 4; ++nt) {
      half8v bhv = bh[nt * 64], blv = bl[nt * 64];
      accm[nt] = __builtin_amdgcn_mfma_f32_16x16x32_f16(al, bhv, accm[nt], 0, 0, 0);
      accm[nt] = __builtin_amdgcn_mfma_f32_16x16x32_f16(ah, blv, accm[nt], 0, 0, 0);
      acc[nt]  = __builtin_amdgcn_mfma_f32_16x16x32_f16(ah, bhv, acc[nt], 0, 0, 0);
    }
  }
  float ps[4] = {0.f, 0.f, 0.f, 0.f}, pd[4] = {0.f, 0.f, 0.f, 0.f};
#pragma unroll
  for (int nt = 0; nt < 4; ++nt) {
    int col = colhalf * 64 + nt * 16 + r;
    float as_ = att_s[col], ad_ = att_d[col];
#pragma unroll
    for (int i = 0; i < 4; ++i) {
      float v = acc[nt][i] + accm[nt][i] * LO_INV;
      int row = row0 + g * 4 + i;
      if (row < nM) C[(size_t)(n0 + row) * 128 + col] = v;
      ps[i] += v * as_;
      pd[i] += v * ad_;
    }
  }
#pragma unroll
  for (int i = 0; i < 4; ++i) {
    for (int off = 1; off < 16; off <<= 1) {
      ps[i] += __shfl_xor(ps[i], off);
      pd[i] += __shfl_xor(pd[i], off);
    }
  }
  if (r == 0) {
#pragma unroll
    for (int i = 0; i < 4; ++i) {
      int row = row0 + g * 4 + i;
      if (row < nM) {
        atomicAdd(&a_s[n0 + row], ps[i]);
        atomicAdd(&a_d[n0 + row], pd[i]);
      }
    }
  }
}

// ---------------------------------------------------------------------------
// Layer-2 aggregate: H=1, C=128. Half-wave per edge, float4 loads.
// ---------------------------------------------------------------------------
__global__ __launch_bounds__(256) void agg2_kernel(
    const float* __restrict__ xw, const float* __restrict__ a_src,
    const float* __restrict__ a_dst, const int* __restrict__ indptr,
    const int* __restrict__ srcs, const float* __restrict__ bias,
    float* __restrict__ out) {
  int lane = threadIdx.x & 63;
  int n = blockIdx.x * 4 + (threadIdx.x >> 6);
  if (n >= N_NODES) return;
  int beg = indptr[n], end = indptr[n + 1];
  int deg = end - beg;
  float adn = a_dst[n];
  int half = lane >> 5, l32 = lane & 31;
  float4 acc = make_float4(0.f, 0.f, 0.f, 0.f);

  auto pairs = [&](int s, float al, int jn) {
    int jj = 0;
    for (; jj + 2 <= jn; jj += 2) {
      int sa = readlane_i(s, jj), sb = readlane_i(s, jj + 1);
      float aa = readlane_f(al, jj), ab = readlane_f(al, jj + 1);
      int sh = half ? sb : sa;
      float ahx = half ? ab : aa;
      float4 v = *(const float4*)&xw[(size_t)sh * HID + l32 * 4];
      acc.x += ahx * v.x; acc.y += ahx * v.y; acc.z += ahx * v.z; acc.w += ahx * v.w;
    }
    if (jj < jn) {
      int sa = readlane_i(s, jj);
      float ahx = half ? 0.f : readlane_f(al, jj);
      float4 v = *(const float4*)&xw[(size_t)sa * HID + l32 * 4];
      acc.x += ahx * v.x; acc.y += ahx * v.y; acc.z += ahx * v.z; acc.w += ahx * v.w;
    }
  };

  if (deg <= 64) {
    int j = beg + lane;
    int s = 0;
    float e = -INFINITY;
    if (j < end) { s = srcs[j]; e = leaky(a_src[s] + adn); }
    float m = e;
    for (int off = 1; off < 64; off <<= 1) m = fmaxf(m, __shfl_xor(m, off));
    float x = (j < end) ? expf(e - m) : 0.f;
    float d = x;
    for (int off = 1; off < 64; off <<= 1) d += __shfl_xor(d, off);
    float al = x / (d + 1e-16f);
    pairs(s, al, deg);
  } else {
    float m = -INFINITY;
    for (int j0 = beg; j0 < end; j0 += 64) {
      int j = j0 + lane;
      if (j < end) m = fmaxf(m, leaky(a_src[srcs[j]] + adn));
    }
    for (int off = 1; off < 64; off <<= 1) m = fmaxf(m, __shfl_xor(m, off));
    float d = 0.f;
    for (int j0 = beg; j0 < end; j0 += 64) {
      int j = j0 + lane;
      if (j < end) d += expf(leaky(a_src[srcs[j]] + adn) - m);
    }
    for (int off = 1; off < 64; off <<= 1) d += __shfl_xor(d, off);
    float rd = 1.f / (d + 1e-16f);
    for (int j0 = beg; j0 < end; j0 += 64) {
      int jn = min(64, end - j0);
      int j = j0 + lane;
      int s = 0;
      float al = 0.f;
      if (j < end) {
        s = srcs[j];
        al = expf(leaky(a_src[s] + adn) - m) * rd;
      }
      pairs(s, al, jn);
    }
  }

  acc.x += __shfl_xor(acc.x, 32); acc.y += __shfl_xor(acc.y, 32);
  acc.z += __shfl_xor(acc.z, 32); acc.w += __shfl_xor(acc.w, 32);
  if (half == 0) {
    float4 b = *(const float4*)&bias[l32 * 4];
    float4 o;
    o.x = elu(acc.x + b.x); o.y = elu(acc.y + b.y);
    o.z = elu(acc.z + b.z); o.w = elu(acc.w + b.w);
    *(float4*)&out[(size_t)n * HID + l32 * 4] = o;
  }
}

// ---------------------------------------------------------------------------
// Graph ranges (batch sorted), two-stage max-pool per graph, classifier head.
// ---------------------------------------------------------------------------
__global__ void gstart_kernel(const int* __restrict__ batch,
                              int* __restrict__ gstarts, int N, int G) {
  int t = threadIdx.x;
  if (t > G) return;
  int lo = 0, hi = N;
  while (lo < hi) {
    int mid = (lo + hi) >> 1;
    if (batch[mid] < t) lo = mid + 1; else hi = mid;
  }
  gstarts[t] = lo;
}

__global__ __launch_bounds__(HID) void pool_part_kernel(
    const float* __restrict__ out2, const int* __restrict__ gstarts,
    float* __restrict__ part) {
  int g = blockIdx.x, s = blockIdx.y, t = threadIdx.x;
  int beg = gstarts[g], end = gstarts[g + 1];
  int len = end - beg;
  int b0 = beg + (int)(((long long)len * s) / POOL_SLICES);
  int b1 = beg + (int)(((long long)len * (s + 1)) / POOL_SLICES);
  float m = -INFINITY;
  for (int n = b0; n < b1; ++n) m = fmaxf(m, out2[(size_t)n * HID + t]);
  part[((size_t)g * POOL_SLICES + s) * HID + t] = m;
}

__global__ __launch_bounds__(HID) void pool_reduce_kernel(
    const float* __restrict__ part, float* __restrict__ pooled) {
  int g = blockIdx.x, t = threadIdx.x;
  float m = -INFINITY;
#pragma unroll
  for (int s = 0; s < POOL_SLICES; ++s)
    m = fmaxf(m, part[((size_t)g * POOL_SLICES + s) * HID + t]);
  pooled[g * HID + t] = m;
}

__global__ __launch_bounds__(HID) void cls_kernel(const float* __restrict__ pooled,
                                                  const float* __restrict__ w1,
                                                  const float* __restrict__ b1,
                                                  const float* __restrict__ w2,
                                                  const float* __restrict__ b2,
                                                  float* __restrict__ out) {
  int g = blockIdx.x, t = threadIdx.x;
  __shared__ float sp[HID], sh1[HID / 2];
  sp[t] = pooled[g * HID + t];
  __syncthreads();
  if (t < HID / 2) {
    float s = b1[t];
    for (int k = 0; k < HID; ++k) s += sp[k] * w1[k * (HID / 2) + t];
    sh1[t] = fmaxf(s, 0.f);
  }
  __syncthreads();
  if (t < 2) {
    float o = b2[t];
    for (int k = 0; k < HID / 2; ++k) o += sh1[k] * w2[k * 2 + t];
    out[g * 2 + t] = o;
  }
}

// ---------------------------------------------------------------------------
extern "C" void kernel_launch(void* const* d_in, const int* in_sizes, int n_in,
                              void* d_out, int out_size, void* d_ws, size_t ws_size,
                              hipStream_t stream) {
  const float* x_scalar = (const float*)d_in[0];
  const int* x_opcode   = (const int*)d_in[1];
  const int* x_source   = (const int*)d_in[2];
  const int* x_sink     = (const int*)d_in[3];
  const int* x_string   = (const int*)d_in[4];
  const int* x_payload  = (const int*)d_in[5];
  const int* edge_index = (const int*)d_in[6];
  const int* batch      = (const int*)d_in[7];
  const float* emb_opcode = (const float*)d_in[8];
  const float* emb_source = (const float*)d_in[9];
  const float* emb_sink   = (const float*)d_in[10];
  const float* emb_string = (const float*)d_in[11];
  const float* emb_payload= (const float*)d_in[12];
  const float* ln_gamma = (const float*)d_in[13];
  const float* ln_beta  = (const float*)d_in[14];
  const float* W1       = (const float*)d_in[15];
  const float* att_src1 = (const float*)d_in[16];
  const float* att_dst1 = (const float*)d_in[17];
  const float* b1       = (const float*)d_in[18];
  const float* W2       = (const float*)d_in[19];
  const float* att_src2 = (const float*)d_in[20];
  const float* att_dst2 = (const float*)d_in[21];
  const float* b2       = (const float*)d_in[22];
  const float* cls_w1   = (const float*)d_in[23];
  const float* cls_b1   = (const float*)d_in[24];
  const float* cls_w2   = (const float*)d_in[25];
  const float* cls_b2   = (const float*)d_in[26];

  // Chunk applies to out1 only (agg1+gemm2 are row-independent).
  auto total_bytes = [&](int chunk) -> size_t {
    size_t f32w = (size_t)N_NODES * IN_DIM          // h (xw2 aliases it later)
                + (size_t)N_NODES * 512             // hw
                + (size_t)chunk * 512               // out1 chunk
                + (size_t)N_NODES * HID             // out2
                + (size_t)N_GRAPHS * HID            // pooled
                + (size_t)N_GRAPHS * POOL_SLICES * HID;  // pool_part
    size_t ints = (N_NODES + 1) + 12 * (size_t)N_NODES + TOT_EDGES + (N_GRAPHS + 1);
    size_t f16e = 2 * (size_t)(PB2_ELEMS + PB1_ELEMS);
    return f32w * 4 + ints * 4 + f16e * 2 + 512;
  };
  int chunk = (ws_size >= total_bytes(N_NODES)) ? N_NODES : CHUNK_SMALL;

  float* h      = (float*)d_ws;                        // [N,176]
  float* hw     = h + (size_t)N_NODES * IN_DIM;        // [N,512] pre-ELU xw
  float* out2   = hw + (size_t)N_NODES * 512;          // [N,128]
  float* pooled = out2 + (size_t)N_NODES * HID;        // [G,128]
  float* pool_part = pooled + N_GRAPHS * HID;          // [G*32*128]
  int* indptr = (int*)(pool_part + (size_t)N_GRAPHS * POOL_SLICES * HID);  // [N+1]
  int* cnt    = indptr + (N_NODES + 1);                // [N]   -- zeroed from here
  int* cursor = cnt + N_NODES;                         // [N]
  float* a2s  = (float*)(cursor + N_NODES);            // [N]
  float* a2d  = a2s + N_NODES;                         // [N]
  float* a1s  = a2d + N_NODES;                         // [N*4]
  float* a1d  = a1s + (size_t)N_NODES * 4;             // [N*4] -- zero ends here
  int* srcs   = (int*)(a1d + (size_t)N_NODES * 4);     // [E+N]
  int* gstarts= srcs + TOT_EDGES;                      // [G+1]
  uintptr_t pal = ((uintptr_t)(gstarts + N_GRAPHS + 1) + 15) & ~(uintptr_t)15;
  _Float16* PB2h = (_Float16*)pal;                     // [65536]
  _Float16* PB2l = PB2h + PB2_ELEMS;                   // [65536]
  _Float16* PB1h = PB2l + PB2_ELEMS;                   // [98304]
  _Float16* PB1l = PB1h + PB1_ELEMS;                   // [98304]
  uintptr_t oal = ((uintptr_t)(PB1l + PB1_ELEMS) + 15) & ~(uintptr_t)15;
  float* out1c = (float*)oal;                          // [chunk*512]
  float* xw2 = h;  // alias: h dead after gemm1; xw2 [N,128] fits in h [N,176]

  // zero cnt, cursor, a2s, a2d, a1s, a1d in one shot (contiguous, 12N words)
  hipMemsetAsync(cnt, 0, 12 * (size_t)N_NODES * sizeof(int), stream);

  const int NB4 = (N_NODES + 3) / 4;
  feats_ln_kernel<<<NB4, 256, 0, stream>>>(
      x_scalar, x_opcode, x_source, x_sink, x_string, x_payload,
      emb_opcode, emb_source, emb_sink, emb_string, emb_payload,
      ln_gamma, ln_beta, h);

  int nthreads = TOT_EDGES;
  count_kernel<<<(nthreads + 255) / 256, 256, 0, stream>>>(edge_index, cnt, N_EDGES, N_NODES);
  prefix_kernel<<<1, 256, 0, stream>>>(cnt, indptr, N_NODES, TOT_EDGES);
  scatter_kernel<<<(nthreads + 255) / 256, 256, 0, stream>>>(edge_index, indptr, cursor, srcs, N_EDGES, N_NODES);

  pack_w1_kernel<<<48, 256, 0, stream>>>(W1, PB1h, PB1l);   // 12288 threads exact
  pack_w2_kernel<<<32, 256, 0, stream>>>(W2, PB2h, PB2l);   // 8192 threads exact

  // hw = h@W1 (pre-ELU) + fused layer-1 attention logits.
  int rgs1 = (N_NODES + 31) / 32;
  gemm1_mfma_kernel<<<rgs1 * 2, 256, 0, stream>>>(
      h, (const half8v*)PB1h, (const half8v*)PB1l, att_src1, att_dst1,
      hw, a1s, a1d, N_NODES);

  for (int n0 = 0; n0 < N_NODES; n0 += chunk) {
    int nM = min(chunk, N_NODES - n0);
    agg1_kernel<<<(nM + 3) / 4, 256, 0, stream>>>(
        hw, a1s, a1d, indptr, srcs, b1, out1c, n0, nM);
    gemm2att_mfma_kernel<<<((nM + 15) / 16 * 2 + 3) / 4, 256, 0, stream>>>(
        out1c, (const half8v*)PB2h, (const half8v*)PB2l, att_src2, att_dst2,
        xw2, a2s, a2d, nM, n0);
  }

  agg2_kernel<<<NB4, 256, 0, stream>>>(xw2, a2s, a2d, indptr, srcs, b2, out2);

  gstart_kernel<<<1, 128, 0, stream>>>(batch, gstarts, N_NODES, N_GRAPHS);
  pool_part_kernel<<<dim3(N_GRAPHS, POOL_SLICES), HID, 0, stream>>>(out2, gstarts, pool_part);
  pool_reduce_kernel<<<N_GRAPHS, HID, 0, stream>>>(pool_part, pooled);
  cls_kernel<<<N_GRAPHS, HID, 0, stream>>>(pooled, cls_w1, cls_b1, cls_w2, cls_b2, (float*)d_out);
}

// Round 6
// 390.800 us; speedup vs baseline: 1.1183x; 1.1183x over previous
//
#include <hip/hip_runtime.h>
#include <hip/hip_bf16.h>
#include <math.h>

// Problem constants (match reference setup_inputs()).
#define N_NODES 20000
#define N_EDGES 320000
#define N_GRAPHS 64
#define SEQ 20
#define SCALAR 16
#define EMB 32
#define HID 128
#define IN_DIM 176         // SCALAR + 5*EMB
#define TOT_EDGES (N_EDGES + N_NODES)  // with self loops
#define CHUNK_SMALL 10000  // fallback node chunk when workspace is tight
#define POOL_SLICES 32     // parallel slices per graph for max-pool

// f16 MFMA types
typedef _Float16 half8v __attribute__((ext_vector_type(8)));
typedef float f32x4 __attribute__((ext_vector_type(4)));
#define LO_SCALE 2048.0f
#define LO_INV (1.0f / 2048.0f)

// Pack-buffer element counts (f16 elems each, hi and lo separately)
#define PB2_ELEMS (16 * 8 * 64 * 8)      // [ks16][ntile8][lane64][j8] = 65536
#define PB1_ELEMS (4 * 6 * 8 * 64 * 8)   // [head4][ks6][ntile8][lane64][j8] = 98304

__device__ inline float readlane_f(float v, int l) {
  return __uint_as_float(__builtin_amdgcn_readlane(__float_as_uint(v), l));
}
__device__ inline int readlane_i(int v, int l) {
  return __builtin_amdgcn_readlane(v, l);
}
__device__ inline float leaky(float e) { return e >= 0.f ? e : 0.2f * e; }
__device__ inline float elu(float v) { return v > 0.f ? v : expf(v) - 1.f; }

// ---------------------------------------------------------------------------
// was/wad precompute, wave-per-k. Runs FIRST (only reads inputs) so the
// fused feats_ln kernel can consume was4/wad4.
// ---------------------------------------------------------------------------
__global__ __launch_bounds__(256) void wasd_kernel(
    const float* __restrict__ W1, const float* __restrict__ att_s,
    const float* __restrict__ att_d, float* __restrict__ was4,
    float* __restrict__ wad4) {
  int lane = threadIdx.x & 63;
  int k = blockIdx.x * 4 + (threadIdx.x >> 6);
  if (k >= IN_DIM) return;
  const float* wrow = W1 + (size_t)k * 512;
  float s[4], d[4];
#pragma unroll
  for (int hh = 0; hh < 4; ++hh) {
    float w0 = wrow[hh * 128 + lane], w1 = wrow[hh * 128 + 64 + lane];
    float a0 = att_s[hh * 128 + lane], a1 = att_s[hh * 128 + 64 + lane];
    float c0 = att_d[hh * 128 + lane], c1 = att_d[hh * 128 + 64 + lane];
    s[hh] = w0 * a0 + w1 * a1;
    d[hh] = w0 * c0 + w1 * c1;
  }
  for (int off = 1; off < 64; off <<= 1) {
#pragma unroll
    for (int hh = 0; hh < 4; ++hh) {
      s[hh] += __shfl_xor(s[hh], off);
      d[hh] += __shfl_xor(d[hh], off);
    }
  }
  if (lane == 0) {
    *(float4*)&was4[k * 4] = make_float4(s[0], s[1], s[2], s[3]);
    *(float4*)&wad4[k * 4] = make_float4(d[0], d[1], d[2], d[3]);
  }
}

// ---------------------------------------------------------------------------
// feats+LN+att1 logits FUSED, wave-per-node (4 nodes / 256-thread block,
// ZERO barriers). The layer-1 attention logits are dotted against the LN'd
// values while they are still in registers — deletes the old att1h kernel
// and its full re-read of h.
// ---------------------------------------------------------------------------
__global__ __launch_bounds__(256) void feats_ln_kernel(
    const float* __restrict__ xs,
    const int* __restrict__ i0, const int* __restrict__ i1,
    const int* __restrict__ i2, const int* __restrict__ i3,
    const int* __restrict__ i4,
    const float* __restrict__ t0, const float* __restrict__ t1,
    const float* __restrict__ t2, const float* __restrict__ t3,
    const float* __restrict__ t4,
    const float* __restrict__ gamma, const float* __restrict__ beta,
    const float* __restrict__ was4, const float* __restrict__ wad4,
    float* __restrict__ hout, float* __restrict__ a_s,
    float* __restrict__ a_d) {
  int lane = threadIdx.x & 63;
  int w = threadIdx.x >> 6;
  int n = blockIdx.x * 4 + w;
  if (n >= N_NODES) return;
  __shared__ int sidx[4][100];
  {
    int j = lane;                       // 0..63 -> tabs 0..3
    int tab = j / 20, l = j - tab * 20;
    const int* ip = tab == 0 ? i0 : tab == 1 ? i1 : tab == 2 ? i2 : i3;
    sidx[w][j] = ip[n * SEQ + l];
    if (lane < 36) {
      int j2 = 64 + lane;               // 64..99 -> tabs 3,4
      int tab2 = j2 / 20, l2 = j2 - tab2 * 20;
      const int* ip2 = tab2 == 3 ? i3 : i4;
      sidx[w][j2] = ip2[n * SEQ + l2];
    }
  }
  bool l48 = lane < 48;
  float f0, f1, f2 = 0.f;
  if (lane < SCALAR) {
    f0 = xs[n * SCALAR + lane];
  } else {
    int tt = lane - SCALAR, tab = tt >> 5, d = tt & 31;  // tab 0 or 1
    const float* tp = tab == 0 ? t0 : t1;
    float sum = 0.f, cnt = 0.f;
#pragma unroll
    for (int l = 0; l < SEQ; ++l) {
      int id = sidx[w][tab * 20 + l];
      if (id != 0) { sum += tp[id * EMB + d]; cnt += 1.f; }
    }
    f0 = sum / (cnt + 1e-9f);
  }
  {
    int tt = 48 + lane, tab = tt >> 5, d = tt & 31;      // tab 1,2,3
    const float* tp = tab == 1 ? t1 : tab == 2 ? t2 : t3;
    float sum = 0.f, cnt = 0.f;
#pragma unroll
    for (int l = 0; l < SEQ; ++l) {
      int id = sidx[w][tab * 20 + l];
      if (id != 0) { sum += tp[id * EMB + d]; cnt += 1.f; }
    }
    f1 = sum / (cnt + 1e-9f);
  }
  if (l48) {
    int tt = 112 + lane, tab = tt >> 5, d = tt & 31;     // tab 3 or 4
    const float* tp = tab == 3 ? t3 : t4;
    float sum = 0.f, cnt = 0.f;
#pragma unroll
    for (int l = 0; l < SEQ; ++l) {
      int id = sidx[w][tab * 20 + l];
      if (id != 0) { sum += tp[id * EMB + d]; cnt += 1.f; }
    }
    f2 = sum / (cnt + 1e-9f);
  }
  float s = f0 + f1 + f2;  // f2==0 for lane>=48
  for (int off = 1; off < 64; off <<= 1) s += __shfl_xor(s, off);
  float mu = s / (float)IN_DIM;
  float v = (f0 - mu) * (f0 - mu) + (f1 - mu) * (f1 - mu) +
            (l48 ? (f2 - mu) * (f2 - mu) : 0.f);
  for (int off = 1; off < 64; off <<= 1) v += __shfl_xor(v, off);
  float rstd = 1.0f / sqrtf(v / (float)IN_DIM + 1e-5f);
  float hv0 = (f0 - mu) * rstd * gamma[lane] + beta[lane];
  float hv1 = (f1 - mu) * rstd * gamma[64 + lane] + beta[64 + lane];
  float hv2 = l48 ? (f2 - mu) * rstd * gamma[128 + lane] + beta[128 + lane] : 0.f;
  float* hr = hout + (size_t)n * IN_DIM;
  hr[lane] = hv0;
  hr[64 + lane] = hv1;
  if (l48) hr[128 + lane] = hv2;

  // Fused layer-1 attention logits (was att1h): ps/pd[h] = h_row . was/wad[:,h]
  const float4* wsv = (const float4*)was4;
  const float4* wdv = (const float4*)wad4;
  float4 wsa = wsv[lane], wsb = wsv[64 + lane];
  float4 wsc = l48 ? wsv[128 + lane] : make_float4(0.f, 0.f, 0.f, 0.f);
  float4 wda = wdv[lane], wdb = wdv[64 + lane];
  float4 wdc = l48 ? wdv[128 + lane] : make_float4(0.f, 0.f, 0.f, 0.f);
  float ps0 = hv0 * wsa.x + hv1 * wsb.x + hv2 * wsc.x;
  float ps1 = hv0 * wsa.y + hv1 * wsb.y + hv2 * wsc.y;
  float ps2 = hv0 * wsa.z + hv1 * wsb.z + hv2 * wsc.z;
  float ps3 = hv0 * wsa.w + hv1 * wsb.w + hv2 * wsc.w;
  float pd0 = hv0 * wda.x + hv1 * wdb.x + hv2 * wdc.x;
  float pd1 = hv0 * wda.y + hv1 * wdb.y + hv2 * wdc.y;
  float pd2 = hv0 * wda.z + hv1 * wdb.z + hv2 * wdc.z;
  float pd3 = hv0 * wda.w + hv1 * wdb.w + hv2 * wdc.w;
  for (int off = 1; off < 64; off <<= 1) {
    ps0 += __shfl_xor(ps0, off); ps1 += __shfl_xor(ps1, off);
    ps2 += __shfl_xor(ps2, off); ps3 += __shfl_xor(ps3, off);
    pd0 += __shfl_xor(pd0, off); pd1 += __shfl_xor(pd1, off);
    pd2 += __shfl_xor(pd2, off); pd3 += __shfl_xor(pd3, off);
  }
  if (lane == 0) {
    *(float4*)&a_s[n * 4] = make_float4(ps0, ps1, ps2, ps3);
    *(float4*)&a_d[n * 4] = make_float4(pd0, pd1, pd2, pd3);
  }
}

// ---------------------------------------------------------------------------
// CSR build.
// ---------------------------------------------------------------------------
__global__ void count_kernel(const int* __restrict__ edge_index,
                             int* __restrict__ cnt, int E, int N) {
  int i = blockIdx.x * blockDim.x + threadIdx.x;
  if (i < E) {
    atomicAdd(&cnt[edge_index[E + i]], 1);
  } else if (i < E + N) {
    atomicAdd(&cnt[i - E], 1);  // self loop dst = node
  }
}

__global__ __launch_bounds__(256) void prefix_kernel(const int* __restrict__ cnt,
                                                     int* __restrict__ indptr,
                                                     int n, int total) {
  __shared__ int ssum[256];
  int t = threadIdx.x;
  int per = (n + 255) / 256;
  int beg = t * per, end = min(beg + per, n);
  int s = 0;
  for (int i = beg; i < end; ++i) s += cnt[i];
  ssum[t] = s;
  __syncthreads();
  if (t == 0) {
    int run = 0;
    for (int i = 0; i < 256; ++i) { int v = ssum[i]; ssum[i] = run; run += v; }
  }
  __syncthreads();
  int run = ssum[t];
  for (int i = beg; i < end; ++i) { indptr[i] = run; run += cnt[i]; }
  if (t == 0) indptr[n] = total;
}

__global__ void scatter_kernel(const int* __restrict__ edge_index,
                               const int* __restrict__ indptr,
                               int* __restrict__ cursor,
                               int* __restrict__ srcs, int E, int N) {
  int i = blockIdx.x * blockDim.x + threadIdx.x;
  int s, d;
  if (i < E) { s = edge_index[i]; d = edge_index[E + i]; }
  else if (i < E + N) { s = i - E; d = s; }
  else return;
  int pos = indptr[d] + atomicAdd(&cursor[d], 1);
  srcs[pos] = s;
}

// ---------------------------------------------------------------------------
// Layer-1 softmax + aggregate h (176-dim) per head -> aggh[(ln*4+h)*176+k].
// (Aggregate in the SMALL dim first — round-5's GEMM-first variant tripled
// gather traffic, 318MB FETCH. Keep this order.)
// ---------------------------------------------------------------------------
__global__ __launch_bounds__(256) void agg1h_kernel(
    const float* __restrict__ h, const float* __restrict__ a_src,
    const float* __restrict__ a_dst, const int* __restrict__ indptr,
    const int* __restrict__ srcs, float* __restrict__ aggh,
    int n0, int nM) {
  int lane = threadIdx.x & 63;
  int ln = blockIdx.x * 4 + (threadIdx.x >> 6);
  if (ln >= nM) return;
  int n = n0 + ln;
  int beg = indptr[n], end = indptr[n + 1];
  int deg = end - beg;
  float4 ad = *(const float4*)&a_dst[n * 4];
  bool l48 = lane < 48;
  float acc[4][3] = {};

  auto body = [&](int s, float al0, float al1, float al2, float al3) {
    const float* r = h + (size_t)s * IN_DIM;
    float v0 = r[lane];
    float v1 = r[64 + lane];
    float v2 = l48 ? r[128 + lane] : 0.f;
    acc[0][0] += al0 * v0; acc[0][1] += al0 * v1; acc[0][2] += al0 * v2;
    acc[1][0] += al1 * v0; acc[1][1] += al1 * v1; acc[1][2] += al1 * v2;
    acc[2][0] += al2 * v0; acc[2][1] += al2 * v1; acc[2][2] += al2 * v2;
    acc[3][0] += al3 * v0; acc[3][1] += al3 * v1; acc[3][2] += al3 * v2;
  };

  if (deg <= 64) {
    int j = beg + lane;
    int s = 0;
    float e0 = -INFINITY, e1 = -INFINITY, e2 = -INFINITY, e3 = -INFINITY;
    if (j < end) {
      s = srcs[j];
      float4 as = *(const float4*)&a_src[s * 4];
      e0 = leaky(as.x + ad.x); e1 = leaky(as.y + ad.y);
      e2 = leaky(as.z + ad.z); e3 = leaky(as.w + ad.w);
    }
    float m0 = e0, m1 = e1, m2 = e2, m3 = e3;
    for (int off = 1; off < 64; off <<= 1) {
      m0 = fmaxf(m0, __shfl_xor(m0, off)); m1 = fmaxf(m1, __shfl_xor(m1, off));
      m2 = fmaxf(m2, __shfl_xor(m2, off)); m3 = fmaxf(m3, __shfl_xor(m3, off));
    }
    float x0 = (j < end) ? expf(e0 - m0) : 0.f;
    float x1 = (j < end) ? expf(e1 - m1) : 0.f;
    float x2 = (j < end) ? expf(e2 - m2) : 0.f;
    float x3 = (j < end) ? expf(e3 - m3) : 0.f;
    float d0 = x0, d1 = x1, d2 = x2, d3 = x3;
    for (int off = 1; off < 64; off <<= 1) {
      d0 += __shfl_xor(d0, off); d1 += __shfl_xor(d1, off);
      d2 += __shfl_xor(d2, off); d3 += __shfl_xor(d3, off);
    }
    float al0 = x0 / (d0 + 1e-16f), al1 = x1 / (d1 + 1e-16f);
    float al2 = x2 / (d2 + 1e-16f), al3 = x3 / (d3 + 1e-16f);
    int jj = 0;
    for (; jj + 2 <= deg; jj += 2) {
      int sa = readlane_i(s, jj), sb = readlane_i(s, jj + 1);
      float a0 = readlane_f(al0, jj), a1 = readlane_f(al1, jj);
      float a2 = readlane_f(al2, jj), a3 = readlane_f(al3, jj);
      float b0 = readlane_f(al0, jj + 1), b1 = readlane_f(al1, jj + 1);
      float b2 = readlane_f(al2, jj + 1), b3 = readlane_f(al3, jj + 1);
      body(sa, a0, a1, a2, a3);
      body(sb, b0, b1, b2, b3);
    }
    if (jj < deg) {
      int sa = readlane_i(s, jj);
      body(sa, readlane_f(al0, jj), readlane_f(al1, jj),
           readlane_f(al2, jj), readlane_f(al3, jj));
    }
  } else {
    float m0 = -INFINITY, m1 = -INFINITY, m2 = -INFINITY, m3 = -INFINITY;
    for (int j0 = beg; j0 < end; j0 += 64) {
      int j = j0 + lane;
      if (j < end) {
        int s = srcs[j];
        float4 as = *(const float4*)&a_src[s * 4];
        m0 = fmaxf(m0, leaky(as.x + ad.x)); m1 = fmaxf(m1, leaky(as.y + ad.y));
        m2 = fmaxf(m2, leaky(as.z + ad.z)); m3 = fmaxf(m3, leaky(as.w + ad.w));
      }
    }
    for (int off = 1; off < 64; off <<= 1) {
      m0 = fmaxf(m0, __shfl_xor(m0, off)); m1 = fmaxf(m1, __shfl_xor(m1, off));
      m2 = fmaxf(m2, __shfl_xor(m2, off)); m3 = fmaxf(m3, __shfl_xor(m3, off));
    }
    float d0 = 0.f, d1 = 0.f, d2 = 0.f, d3 = 0.f;
    for (int j0 = beg; j0 < end; j0 += 64) {
      int j = j0 + lane;
      if (j < end) {
        int s = srcs[j];
        float4 as = *(const float4*)&a_src[s * 4];
        d0 += expf(leaky(as.x + ad.x) - m0); d1 += expf(leaky(as.y + ad.y) - m1);
        d2 += expf(leaky(as.z + ad.z) - m2); d3 += expf(leaky(as.w + ad.w) - m3);
      }
    }
    for (int off = 1; off < 64; off <<= 1) {
      d0 += __shfl_xor(d0, off); d1 += __shfl_xor(d1, off);
      d2 += __shfl_xor(d2, off); d3 += __shfl_xor(d3, off);
    }
    float r0 = 1.f / (d0 + 1e-16f), r1 = 1.f / (d1 + 1e-16f);
    float r2 = 1.f / (d2 + 1e-16f), r3 = 1.f / (d3 + 1e-16f);
    for (int j0 = beg; j0 < end; j0 += 64) {
      int jn = min(64, end - j0);
      int j = j0 + lane;
      int s = 0;
      float al0 = 0.f, al1 = 0.f, al2 = 0.f, al3 = 0.f;
      if (j < end) {
        s = srcs[j];
        float4 as = *(const float4*)&a_src[s * 4];
        al0 = expf(leaky(as.x + ad.x) - m0) * r0;
        al1 = expf(leaky(as.y + ad.y) - m1) * r1;
        al2 = expf(leaky(as.z + ad.z) - m2) * r2;
        al3 = expf(leaky(as.w + ad.w) - m3) * r3;
      }
      for (int jj = 0; jj < jn; ++jj) {
        body(readlane_i(s, jj), readlane_f(al0, jj), readlane_f(al1, jj),
             readlane_f(al2, jj), readlane_f(al3, jj));
      }
    }
  }

  size_t base = (size_t)ln * (4 * IN_DIM);
#pragma unroll
  for (int hh = 0; hh < 4; ++hh) {
    aggh[base + hh * IN_DIM + lane] = acc[hh][0];
    aggh[base + hh * IN_DIM + 64 + lane] = acc[hh][1];
    if (l48) aggh[base + hh * IN_DIM + 128 + lane] = acc[hh][2];
  }
}

// ---------------------------------------------------------------------------
// Pack W2 [512,128] fp32 -> f16 hi/lo fragments for mfma_f32_16x16x32_f16.
// Layout: [ks(16)][ntile(8)][lane(64)][j(8)]; elem = W2[ks*32+(l>>4)*8+j][nt*16+(l&15)].
// lo pre-scaled by 2048 to stay in f16 normal range.
// ---------------------------------------------------------------------------
__global__ __launch_bounds__(256) void pack_w2_kernel(
    const float* __restrict__ W2, _Float16* __restrict__ PBh,
    _Float16* __restrict__ PBl) {
  int t = blockIdx.x * 256 + threadIdx.x;  // 8192 threads exactly
  int lane = t & 63, wi = t >> 6;          // wi = ks*8 + ntile
  int r = lane & 15, g = lane >> 4;
  int ks = wi >> 3, ntile = wi & 7;
  int col = ntile * 16 + r;
  size_t o = ((size_t)wi * 64 + lane) * 8;
#pragma unroll
  for (int j = 0; j < 8; ++j) {
    int k = ks * 32 + g * 8 + j;
    float v = W2[(size_t)k * 128 + col];
    _Float16 h = (_Float16)v;
    PBh[o + j] = h;
    PBl[o + j] = (_Float16)((v - (float)h) * LO_SCALE);
  }
}

// ---------------------------------------------------------------------------
// Pack W1 [176,512] fp32 -> per-head f16 hi/lo fragments, K zero-padded to 192.
// Layout: [hh(4)][ks(6)][ntile(8)][lane(64)][j(8)];
// elem = W1[k][hh*128 + ntile*16 + (l&15)], k = ks*32+(l>>4)*8+j, 0 if k>=176.
// ---------------------------------------------------------------------------
__global__ __launch_bounds__(256) void pack_w1_kernel(
    const float* __restrict__ W1, _Float16* __restrict__ PBh,
    _Float16* __restrict__ PBl) {
  int t = blockIdx.x * 256 + threadIdx.x;  // 12288 threads exactly
  int lane = t & 63, wi = t >> 6;          // wi = (hh*6+ks)*8 + ntile
  int r = lane & 15, g = lane >> 4;
  int ntile = wi & 7, rem = wi >> 3;
  int ks = rem % 6, hh = rem / 6;
  int col = hh * 128 + ntile * 16 + r;
  size_t o = ((size_t)wi * 64 + lane) * 8;
#pragma unroll
  for (int j = 0; j < 8; ++j) {
    int k = ks * 32 + g * 8 + j;
    float v = (k < IN_DIM) ? W1[(size_t)k * 512 + col] : 0.f;
    _Float16 h = (_Float16)v;
    PBh[o + j] = h;
    PBl[o + j] = (_Float16)((v - (float)h) * LO_SCALE);
  }
}

// ---------------------------------------------------------------------------
// Head-GEMM via f16 hi/lo MFMA (3-product fp32 emulation). LDS-free, no
// barriers. Wave = 32 rows x 64 cols of one head: wid = (rg*4+hh)*2+colhalf.
// A-frag: lane reads aggh row (rows0+mt*16+(l&15)), k = ks*32+(l>>4)*8..+7
// as 2x dwordx4, converted to f16 hi + 2048*lo in-register. B pre-packed.
// K padded to 192: the ks=5 tail CLAMPS the A k-offset in-row (koff=0) so
// loads stay on live finite data; B's zeros kill the wrong values.
// out = acc_hi + acc_mid/2048, elu+bias epilogue, f32 stores (f16 stores
// inflated WRITE_SIZE 40->72MB in round 4 — keep f32).
// ---------------------------------------------------------------------------
__global__ __launch_bounds__(256) void gemm_head_mfma_kernel(
    const float* __restrict__ aggh, const half8v* __restrict__ PBh,
    const half8v* __restrict__ PBl, const float* __restrict__ b1,
    float* __restrict__ out1, int M, int n0) {
  int lane = threadIdx.x & 63;
  int wid = (blockIdx.x * 256 + threadIdx.x) >> 6;
  int colhalf = wid & 1;
  int hh = (wid >> 1) & 3;
  int rg = wid >> 3;
  int rows0 = rg * 32;
  if (rows0 >= M) return;
  int r = lane & 15, g = lane >> 4;
  f32x4 acc[2][4] = {};
  f32x4 accm[2][4] = {};
  const float* a0 = aggh + ((size_t)(rows0 + r) * 4 + hh) * IN_DIM;
  const float* a1 = aggh + ((size_t)(rows0 + 16 + r) * 4 + hh) * IN_DIM;
#pragma unroll 2
  for (int ks = 0; ks < 6; ++ks) {
    int kg = ks * 32 + g * 8;
    int koff = (kg + 8 <= IN_DIM) ? kg : 0;  // clamp tail in-row (B zeros kill it)
    half8v ah[2], al[2];
#pragma unroll
    for (int mt = 0; mt < 2; ++mt) {
      const float* ap = (mt ? a1 : a0) + koff;
      float av[8];
      *(float4*)&av[0] = *(const float4*)(ap);
      *(float4*)&av[4] = *(const float4*)(ap + 4);
#pragma unroll
      for (int j = 0; j < 8; ++j) {
        _Float16 hv = (_Float16)av[j];
        ah[mt][j] = hv;
        al[mt][j] = (_Float16)((av[j] - (float)hv) * LO_SCALE);
      }
    }
    const half8v* bh = PBh + (size_t)(((hh * 6 + ks) * 8 + colhalf * 4) * 64) + lane;
    const half8v* bl = PBl + (size_t)(((hh * 6 + ks) * 8 + colhalf * 4) * 64) + lane;
#pragma unroll
    for (int nt = 0; nt < 4; ++nt) {
      half8v bhv = bh[nt * 64], blv = bl[nt * 64];
#pragma unroll
      for (int mt = 0; mt < 2; ++mt) {
        accm[mt][nt] = __builtin_amdgcn_mfma_f32_16x16x32_f16(al[mt], bhv, accm[mt][nt], 0, 0, 0);
        accm[mt][nt] = __builtin_amdgcn_mfma_f32_16x16x32_f16(ah[mt], blv, accm[mt][nt], 0, 0, 0);
        acc[mt][nt]  = __builtin_amdgcn_mfma_f32_16x16x32_f16(ah[mt], bhv, acc[mt][nt], 0, 0, 0);
      }
    }
  }
#pragma unroll
  for (int nt = 0; nt < 4; ++nt) {
    int col = hh * 128 + colhalf * 64 + nt * 16 + r;
    float bb = b1[col];
#pragma unroll
    for (int mt = 0; mt < 2; ++mt) {
#pragma unroll
      for (int i = 0; i < 4; ++i) {
        int row = rows0 + mt * 16 + g * 4 + i;
        if (row < M)
          out1[(size_t)(n0 + row) * 512 + col] =
              elu(acc[mt][nt][i] + accm[mt][nt][i] * LO_INV + bb);
      }
    }
  }
}

// ---------------------------------------------------------------------------
// GEMM2 (out1@W2) via f16 hi/lo MFMA + fused layer-2 att logits.
// Wave = 16 rows x 64 cols; wid = rg*2+colhalf (2500 waves / 625 blocks).
// a2s/a2d: per-row dot with att vectors, 16-lane shfl reduce + 1 atomic
// per row-half (pre-zeroed).
// ---------------------------------------------------------------------------
__global__ __launch_bounds__(256) void gemm2att_mfma_kernel(
    const float* __restrict__ A, const half8v* __restrict__ PBh,
    const half8v* __restrict__ PBl, const float* __restrict__ att_s,
    const float* __restrict__ att_d, float* __restrict__ C,
    float* __restrict__ a_s, float* __restrict__ a_d, int M) {
  int lane = threadIdx.x & 63;
  int wid = (blockIdx.x * 256 + threadIdx.x) >> 6;
  int colhalf = wid & 1;
  int rg = wid >> 1;
  int row0 = rg * 16;
  if (row0 >= M) return;
  int r = lane & 15, g = lane >> 4;
  const float* arow = A + (size_t)(row0 + r) * 512 + g * 8;
  f32x4 acc[4] = {};
  f32x4 accm[4] = {};
#pragma unroll 2
  for (int ks = 0; ks < 16; ++ks) {
    float av[8];
    *(float4*)&av[0] = *(const float4*)(arow + ks * 32);
    *(float4*)&av[4] = *(const float4*)(arow + ks * 32 + 4);
    half8v ah, al;
#pragma unroll
    for (int j = 0; j < 8; ++j) {
      _Float16 hv = (_Float16)av[j];
      ah[j] = hv;
      al[j] = (_Float16)((av[j] - (float)hv) * LO_SCALE);
    }
    const half8v* bh = PBh + (size_t)((ks * 8 + colhalf * 4) * 64) + lane;
    const half8v* bl = PBl + (size_t)((ks * 8 + colhalf * 4) * 64) + lane;
#pragma unroll
    for (int nt = 0; nt < 4; ++nt) {
      half8v bhv = bh[nt * 64], blv = bl[nt * 64];
      accm[nt] = __builtin_amdgcn_mfma_f32_16x16x32_f16(al, bhv, accm[nt], 0, 0, 0);
      accm[nt] = __builtin_amdgcn_mfma_f32_16x16x32_f16(ah, blv, accm[nt], 0, 0, 0);
      acc[nt]  = __builtin_amdgcn_mfma_f32_16x16x32_f16(ah, bhv, acc[nt], 0, 0, 0);
    }
  }
  float ps[4] = {0.f, 0.f, 0.f, 0.f}, pd[4] = {0.f, 0.f, 0.f, 0.f};
#pragma unroll
  for (int nt = 0; nt < 4; ++nt) {
    int col = colhalf * 64 + nt * 16 + r;
    float as_ = att_s[col], ad_ = att_d[col];
#pragma unroll
    for (int i = 0; i < 4; ++i) {
      float v = acc[nt][i] + accm[nt][i] * LO_INV;
      int row = row0 + g * 4 + i;
      C[(size_t)row * 128 + col] = v;
      ps[i] += v * as_;
      pd[i] += v * ad_;
    }
  }
#pragma unroll
  for (int i = 0; i < 4; ++i) {
    for (int off = 1; off < 16; off <<= 1) {
      ps[i] += __shfl_xor(ps[i], off);
      pd[i] += __shfl_xor(pd[i], off);
    }
  }
  if (r == 0) {
#pragma unroll
    for (int i = 0; i < 4; ++i) {
      atomicAdd(&a_s[row0 + g * 4 + i], ps[i]);
      atomicAdd(&a_d[row0 + g * 4 + i], pd[i]);
    }
  }
}

// ---------------------------------------------------------------------------
// Layer-2 aggregate: H=1, C=128. Half-wave per edge, float4 loads.
// ---------------------------------------------------------------------------
__global__ __launch_bounds__(256) void agg2_kernel(
    const float* __restrict__ xw, const float* __restrict__ a_src,
    const float* __restrict__ a_dst, const int* __restrict__ indptr,
    const int* __restrict__ srcs, const float* __restrict__ bias,
    float* __restrict__ out) {
  int lane = threadIdx.x & 63;
  int n = blockIdx.x * 4 + (threadIdx.x >> 6);
  if (n >= N_NODES) return;
  int beg = indptr[n], end = indptr[n + 1];
  int deg = end - beg;
  float adn = a_dst[n];
  int half = lane >> 5, l32 = lane & 31;
  float4 acc = make_float4(0.f, 0.f, 0.f, 0.f);

  auto pairs = [&](int s, float al, int jn) {
    int jj = 0;
    for (; jj + 2 <= jn; jj += 2) {
      int sa = readlane_i(s, jj), sb = readlane_i(s, jj + 1);
      float aa = readlane_f(al, jj), ab = readlane_f(al, jj + 1);
      int sh = half ? sb : sa;
      float ahx = half ? ab : aa;
      float4 v = *(const float4*)&xw[(size_t)sh * HID + l32 * 4];
      acc.x += ahx * v.x; acc.y += ahx * v.y; acc.z += ahx * v.z; acc.w += ahx * v.w;
    }
    if (jj < jn) {
      int sa = readlane_i(s, jj);
      float ahx = half ? 0.f : readlane_f(al, jj);
      float4 v = *(const float4*)&xw[(size_t)sa * HID + l32 * 4];
      acc.x += ahx * v.x; acc.y += ahx * v.y; acc.z += ahx * v.z; acc.w += ahx * v.w;
    }
  };

  if (deg <= 64) {
    int j = beg + lane;
    int s = 0;
    float e = -INFINITY;
    if (j < end) { s = srcs[j]; e = leaky(a_src[s] + adn); }
    float m = e;
    for (int off = 1; off < 64; off <<= 1) m = fmaxf(m, __shfl_xor(m, off));
    float x = (j < end) ? expf(e - m) : 0.f;
    float d = x;
    for (int off = 1; off < 64; off <<= 1) d += __shfl_xor(d, off);
    float al = x / (d + 1e-16f);
    pairs(s, al, deg);
  } else {
    float m = -INFINITY;
    for (int j0 = beg; j0 < end; j0 += 64) {
      int j = j0 + lane;
      if (j < end) m = fmaxf(m, leaky(a_src[srcs[j]] + adn));
    }
    for (int off = 1; off < 64; off <<= 1) m = fmaxf(m, __shfl_xor(m, off));
    float d = 0.f;
    for (int j0 = beg; j0 < end; j0 += 64) {
      int j = j0 + lane;
      if (j < end) d += expf(leaky(a_src[srcs[j]] + adn) - m);
    }
    for (int off = 1; off < 64; off <<= 1) d += __shfl_xor(d, off);
    float rd = 1.f / (d + 1e-16f);
    for (int j0 = beg; j0 < end; j0 += 64) {
      int jn = min(64, end - j0);
      int j = j0 + lane;
      int s = 0;
      float al = 0.f;
      if (j < end) {
        s = srcs[j];
        al = expf(leaky(a_src[s] + adn) - m) * rd;
      }
      pairs(s, al, jn);
    }
  }

  acc.x += __shfl_xor(acc.x, 32); acc.y += __shfl_xor(acc.y, 32);
  acc.z += __shfl_xor(acc.z, 32); acc.w += __shfl_xor(acc.w, 32);
  if (half == 0) {
    float4 b = *(const float4*)&bias[l32 * 4];
    float4 o;
    o.x = elu(acc.x + b.x); o.y = elu(acc.y + b.y);
    o.z = elu(acc.z + b.z); o.w = elu(acc.w + b.w);
    *(float4*)&out[(size_t)n * HID + l32 * 4] = o;
  }
}

// ---------------------------------------------------------------------------
// Graph ranges (batch sorted), two-stage max-pool per graph, classifier head.
// ---------------------------------------------------------------------------
__global__ void gstart_kernel(const int* __restrict__ batch,
                              int* __restrict__ gstarts, int N, int G) {
  int t = threadIdx.x;
  if (t > G) return;
  int lo = 0, hi = N;
  while (lo < hi) {
    int mid = (lo + hi) >> 1;
    if (batch[mid] < t) lo = mid + 1; else hi = mid;
  }
  gstarts[t] = lo;
}

__global__ __launch_bounds__(HID) void pool_part_kernel(
    const float* __restrict__ out2, const int* __restrict__ gstarts,
    float* __restrict__ part) {
  int g = blockIdx.x, s = blockIdx.y, t = threadIdx.x;
  int beg = gstarts[g], end = gstarts[g + 1];
  int len = end - beg;
  int b0 = beg + (int)(((long long)len * s) / POOL_SLICES);
  int b1 = beg + (int)(((long long)len * (s + 1)) / POOL_SLICES);
  float m = -INFINITY;
  for (int n = b0; n < b1; ++n) m = fmaxf(m, out2[(size_t)n * HID + t]);
  part[((size_t)g * POOL_SLICES + s) * HID + t] = m;
}

__global__ __launch_bounds__(HID) void pool_reduce_kernel(
    const float* __restrict__ part, float* __restrict__ pooled) {
  int g = blockIdx.x, t = threadIdx.x;
  float m = -INFINITY;
#pragma unroll
  for (int s = 0; s < POOL_SLICES; ++s)
    m = fmaxf(m, part[((size_t)g * POOL_SLICES + s) * HID + t]);
  pooled[g * HID + t] = m;
}

__global__ __launch_bounds__(HID) void cls_kernel(const float* __restrict__ pooled,
                                                  const float* __restrict__ w1,
                                                  const float* __restrict__ b1,
                                                  const float* __restrict__ w2,
                                                  const float* __restrict__ b2,
                                                  float* __restrict__ out) {
  int g = blockIdx.x, t = threadIdx.x;
  __shared__ float sp[HID], sh1[HID / 2];
  sp[t] = pooled[g * HID + t];
  __syncthreads();
  if (t < HID / 2) {
    float s = b1[t];
    for (int k = 0; k < HID; ++k) s += sp[k] * w1[k * (HID / 2) + t];
    sh1[t] = fmaxf(s, 0.f);
  }
  __syncthreads();
  if (t < 2) {
    float o = b2[t];
    for (int k = 0; k < HID / 2; ++k) o += sh1[k] * w2[k * 2 + t];
    out[g * 2 + t] = o;
  }
}

// ---------------------------------------------------------------------------
extern "C" void kernel_launch(void* const* d_in, const int* in_sizes, int n_in,
                              void* d_out, int out_size, void* d_ws, size_t ws_size,
                              hipStream_t stream) {
  const float* x_scalar = (const float*)d_in[0];
  const int* x_opcode   = (const int*)d_in[1];
  const int* x_source   = (const int*)d_in[2];
  const int* x_sink     = (const int*)d_in[3];
  const int* x_string   = (const int*)d_in[4];
  const int* x_payload  = (const int*)d_in[5];
  const int* edge_index = (const int*)d_in[6];
  const int* batch      = (const int*)d_in[7];
  const float* emb_opcode = (const float*)d_in[8];
  const float* emb_source = (const float*)d_in[9];
  const float* emb_sink   = (const float*)d_in[10];
  const float* emb_string = (const float*)d_in[11];
  const float* emb_payload= (const float*)d_in[12];
  const float* ln_gamma = (const float*)d_in[13];
  const float* ln_beta  = (const float*)d_in[14];
  const float* W1       = (const float*)d_in[15];
  const float* att_src1 = (const float*)d_in[16];
  const float* att_dst1 = (const float*)d_in[17];
  const float* b1       = (const float*)d_in[18];
  const float* W2       = (const float*)d_in[19];
  const float* att_src2 = (const float*)d_in[20];
  const float* att_dst2 = (const float*)d_in[21];
  const float* b2       = (const float*)d_in[22];
  const float* cls_w1   = (const float*)d_in[23];
  const float* cls_b1   = (const float*)d_in[24];
  const float* cls_w2   = (const float*)d_in[25];
  const float* cls_b2   = (const float*)d_in[26];

  // Adaptive chunk: run layer-1 agg + head-GEMM in 1 pass if workspace allows.
  auto total_bytes = [&](int chunk) -> size_t {
    size_t f = (size_t)N_NODES * IN_DIM + (size_t)chunk * 4 * IN_DIM +
               (size_t)N_NODES * 512 + (size_t)N_NODES * HID +
               N_NODES * 4 * 2 + N_NODES * 2 + IN_DIM * 4 * 2 + N_GRAPHS * HID;
    size_t ii = (N_NODES + 1) + N_NODES * 2 + TOT_EDGES + (N_GRAPHS + 1);
    size_t f16b = (size_t)2 * (PB2_ELEMS + PB1_ELEMS) * sizeof(_Float16) + 32;
    size_t poolb = (size_t)N_GRAPHS * POOL_SLICES * HID * 4 + 32;
    return f * 4 + ii * 4 + f16b + poolb + 256;
  };
  int chunk = (ws_size >= total_bytes(N_NODES)) ? N_NODES : CHUNK_SMALL;

  float* h      = (float*)d_ws;                        // [N,176]
  float* aggh   = h + (size_t)N_NODES * IN_DIM;        // [chunk*704]
  float* out1   = aggh + (size_t)chunk * 4 * IN_DIM;   // [N,512]
  float* out2   = out1 + (size_t)N_NODES * 512;        // [N,128]
  float* a1s    = out2 + (size_t)N_NODES * HID;        // [N,4]
  float* a1d    = a1s + N_NODES * 4;
  float* was4   = a1d + N_NODES * 4;                   // [176*4]
  float* wad4   = was4 + IN_DIM * 4;                   // [176*4]
  float* pooled = wad4 + IN_DIM * 4;                   // [G,128]
  int* indptr = (int*)(pooled + N_GRAPHS * HID);       // [N+1]
  int* cnt    = indptr + (N_NODES + 1);                // [N]   (zeroed)
  int* cursor = cnt + N_NODES;                         // [N]   (zeroed)
  float* a2s  = (float*)(cursor + N_NODES);            // [N]   (zeroed)
  float* a2d  = a2s + N_NODES;                         // [N]   (zeroed)
  int* srcs   = (int*)(a2d + N_NODES);                 // [E+N]
  int* gstarts= srcs + TOT_EDGES;                      // [G+1]
  // f16 pack buffers, 16B-aligned (half8v loads)
  uintptr_t pal = ((uintptr_t)(gstarts + N_GRAPHS + 1) + 15) & ~(uintptr_t)15;
  _Float16* PB2h = (_Float16*)pal;                     // [65536]
  _Float16* PB2l = PB2h + PB2_ELEMS;                   // [65536]
  _Float16* PB1h = PB2l + PB2_ELEMS;                   // [98304]
  _Float16* PB1l = PB1h + PB1_ELEMS;                   // [98304]
  uintptr_t ppal = ((uintptr_t)(PB1l + PB1_ELEMS) + 15) & ~(uintptr_t)15;
  float* pool_part = (float*)ppal;                     // [G*32*128]
  float* xw2  = h;  // alias: h dead after last agg1h; xw2 [N,128] fits in h [N,176]

  // zero cnt, cursor, a2s, a2d in one shot (contiguous)
  hipMemsetAsync(cnt, 0, 4 * N_NODES * sizeof(int), stream);

  const int NB4 = (N_NODES + 3) / 4;

  // wasd first (inputs only) so feats_ln can fuse the att1 logits.
  wasd_kernel<<<(IN_DIM + 3) / 4, 256, 0, stream>>>(W1, att_src1, att_dst1, was4, wad4);

  feats_ln_kernel<<<NB4, 256, 0, stream>>>(
      x_scalar, x_opcode, x_source, x_sink, x_string, x_payload,
      emb_opcode, emb_source, emb_sink, emb_string, emb_payload,
      ln_gamma, ln_beta, was4, wad4, h, a1s, a1d);

  int nthreads = TOT_EDGES;
  count_kernel<<<(nthreads + 255) / 256, 256, 0, stream>>>(edge_index, cnt, N_EDGES, N_NODES);
  prefix_kernel<<<1, 256, 0, stream>>>(cnt, indptr, N_NODES, TOT_EDGES);
  scatter_kernel<<<(nthreads + 255) / 256, 256, 0, stream>>>(edge_index, indptr, cursor, srcs, N_EDGES, N_NODES);

  pack_w1_kernel<<<48, 256, 0, stream>>>(W1, PB1h, PB1l);   // 12288 threads exact
  pack_w2_kernel<<<32, 256, 0, stream>>>(W2, PB2h, PB2l);   // 8192 threads exact

  for (int n0 = 0; n0 < N_NODES; n0 += chunk) {
    int nM = min(chunk, N_NODES - n0);
    agg1h_kernel<<<(nM + 3) / 4, 256, 0, stream>>>(h, a1s, a1d, indptr, srcs, aggh, n0, nM);
    int rgs = (nM + 31) / 32;           // 32 rows per wave-group
    gemm_head_mfma_kernel<<<rgs * 2, 256, 0, stream>>>(   // rgs*8 waves / 4 per block
        aggh, (const half8v*)PB1h, (const half8v*)PB1l, b1, out1, nM, n0);
  }

  // GEMM2 + fused att2 logits via MFMA: 2500 waves = 625 blocks.
  gemm2att_mfma_kernel<<<((N_NODES + 15) / 16 * 2 + 3) / 4, 256, 0, stream>>>(
      out1, (const half8v*)PB2h, (const half8v*)PB2l, att_src2, att_dst2,
      xw2, a2s, a2d, N_NODES);

  agg2_kernel<<<NB4, 256, 0, stream>>>(xw2, a2s, a2d, indptr, srcs, b2, out2);

  gstart_kernel<<<1, 128, 0, stream>>>(batch, gstarts, N_NODES, N_GRAPHS);
  pool_part_kernel<<<dim3(N_GRAPHS, POOL_SLICES), HID, 0, stream>>>(out2, gstarts, pool_part);
  pool_reduce_kernel<<<N_GRAPHS, HID, 0, stream>>>(pool_part, pooled);
  cls_kernel<<<N_GRAPHS, HID, 0, stream>>>(pooled, cls_w1, cls_b1, cls_w2, cls_b2, (float*)d_out);
}

// Round 7
// 382.037 us; speedup vs baseline: 1.1439x; 1.0229x over previous
//
#include <hip/hip_runtime.h>
#include <hip/hip_bf16.h>
#include <math.h>

// Problem constants (match reference setup_inputs()).
#define N_NODES 20000
#define N_EDGES 320000
#define N_GRAPHS 64
#define SEQ 20
#define SCALAR 16
#define EMB 32
#define HID 128
#define IN_DIM 176         // SCALAR + 5*EMB
#define TOT_EDGES (N_EDGES + N_NODES)  // with self loops
#define CHUNK_SMALL 10000  // fallback node chunk when workspace is tight
#define POOL_SLICES 32     // parallel slices per graph for max-pool

// f16 MFMA types
typedef _Float16 half8v __attribute__((ext_vector_type(8)));
typedef float f32x4 __attribute__((ext_vector_type(4)));
#define LO_SCALE 2048.0f
#define LO_INV (1.0f / 2048.0f)

// Pack-buffer element counts (f16 elems each, hi and lo separately)
#define PB2_ELEMS (16 * 8 * 64 * 8)      // [ks16][ntile8][lane64][j8] = 65536
#define PB1_ELEMS (4 * 6 * 8 * 64 * 8)   // [head4][ks6][ntile8][lane64][j8] = 98304

__device__ inline float readlane_f(float v, int l) {
  return __uint_as_float(__builtin_amdgcn_readlane(__float_as_uint(v), l));
}
__device__ inline int readlane_i(int v, int l) {
  return __builtin_amdgcn_readlane(v, l);
}
__device__ inline float leaky(float e) { return e >= 0.f ? e : 0.2f * e; }
__device__ inline float elu(float v) { return v > 0.f ? v : expf(v) - 1.f; }

// ---------------------------------------------------------------------------
// SETUP (one launch): wasd precompute + W1/W2 f16 hi/lo packing.
// blocks [0,44): wasd (4 k rows each); [44,92): pack_w1; [92,124): pack_w2.
// All read only kernel inputs -> safe to run first.
// ---------------------------------------------------------------------------
__global__ __launch_bounds__(256) void setup_kernel(
    const float* __restrict__ W1, const float* __restrict__ att_s1,
    const float* __restrict__ att_d1, const float* __restrict__ W2,
    float* __restrict__ was4, float* __restrict__ wad4,
    _Float16* __restrict__ PB1h, _Float16* __restrict__ PB1l,
    _Float16* __restrict__ PB2h, _Float16* __restrict__ PB2l) {
  int b = blockIdx.x;
  if (b < 44) {
    // wasd: was/wad[k][h] = sum_c W1[k, h*128+c] * att[h*128+c]
    int lane = threadIdx.x & 63;
    int k = b * 4 + (threadIdx.x >> 6);
    if (k >= IN_DIM) return;
    const float* wrow = W1 + (size_t)k * 512;
    float s[4], d[4];
#pragma unroll
    for (int hh = 0; hh < 4; ++hh) {
      float w0 = wrow[hh * 128 + lane], w1 = wrow[hh * 128 + 64 + lane];
      float a0 = att_s1[hh * 128 + lane], a1 = att_s1[hh * 128 + 64 + lane];
      float c0 = att_d1[hh * 128 + lane], c1 = att_d1[hh * 128 + 64 + lane];
      s[hh] = w0 * a0 + w1 * a1;
      d[hh] = w0 * c0 + w1 * c1;
    }
    for (int off = 1; off < 64; off <<= 1) {
#pragma unroll
      for (int hh = 0; hh < 4; ++hh) {
        s[hh] += __shfl_xor(s[hh], off);
        d[hh] += __shfl_xor(d[hh], off);
      }
    }
    if (lane == 0) {
      *(float4*)&was4[k * 4] = make_float4(s[0], s[1], s[2], s[3]);
      *(float4*)&wad4[k * 4] = make_float4(d[0], d[1], d[2], d[3]);
    }
  } else if (b < 92) {
    // pack_w1: [hh4][ks6][ntile8][lane64][j8], K zero-padded to 192.
    int t = (b - 44) * 256 + threadIdx.x;  // 12288 threads exactly
    int lane = t & 63, wi = t >> 6;
    int r = lane & 15, g = lane >> 4;
    int ntile = wi & 7, rem = wi >> 3;
    int ks = rem % 6, hh = rem / 6;
    int col = hh * 128 + ntile * 16 + r;
    size_t o = ((size_t)wi * 64 + lane) * 8;
#pragma unroll
    for (int j = 0; j < 8; ++j) {
      int k = ks * 32 + g * 8 + j;
      float v = (k < IN_DIM) ? W1[(size_t)k * 512 + col] : 0.f;
      _Float16 h = (_Float16)v;
      PB1h[o + j] = h;
      PB1l[o + j] = (_Float16)((v - (float)h) * LO_SCALE);
    }
  } else {
    // pack_w2: [ks16][ntile8][lane64][j8]
    int t = (b - 92) * 256 + threadIdx.x;  // 8192 threads exactly
    int lane = t & 63, wi = t >> 6;
    int r = lane & 15, g = lane >> 4;
    int ks = wi >> 3, ntile = wi & 7;
    int col = ntile * 16 + r;
    size_t o = ((size_t)wi * 64 + lane) * 8;
#pragma unroll
    for (int j = 0; j < 8; ++j) {
      int k = ks * 32 + g * 8 + j;
      float v = W2[(size_t)k * 128 + col];
      _Float16 h = (_Float16)v;
      PB2h[o + j] = h;
      PB2l[o + j] = (_Float16)((v - (float)h) * LO_SCALE);
    }
  }
}

// ---------------------------------------------------------------------------
// feats+LN+att1 logits FUSED, wave-per-node (4 nodes / 256-thread block,
// ZERO barriers).
// ---------------------------------------------------------------------------
__global__ __launch_bounds__(256) void feats_ln_kernel(
    const float* __restrict__ xs,
    const int* __restrict__ i0, const int* __restrict__ i1,
    const int* __restrict__ i2, const int* __restrict__ i3,
    const int* __restrict__ i4,
    const float* __restrict__ t0, const float* __restrict__ t1,
    const float* __restrict__ t2, const float* __restrict__ t3,
    const float* __restrict__ t4,
    const float* __restrict__ gamma, const float* __restrict__ beta,
    const float* __restrict__ was4, const float* __restrict__ wad4,
    float* __restrict__ hout, float* __restrict__ a_s,
    float* __restrict__ a_d) {
  int lane = threadIdx.x & 63;
  int w = threadIdx.x >> 6;
  int n = blockIdx.x * 4 + w;
  if (n >= N_NODES) return;
  __shared__ int sidx[4][100];
  {
    int j = lane;                       // 0..63 -> tabs 0..3
    int tab = j / 20, l = j - tab * 20;
    const int* ip = tab == 0 ? i0 : tab == 1 ? i1 : tab == 2 ? i2 : i3;
    sidx[w][j] = ip[n * SEQ + l];
    if (lane < 36) {
      int j2 = 64 + lane;               // 64..99 -> tabs 3,4
      int tab2 = j2 / 20, l2 = j2 - tab2 * 20;
      const int* ip2 = tab2 == 3 ? i3 : i4;
      sidx[w][j2] = ip2[n * SEQ + l2];
    }
  }
  bool l48 = lane < 48;
  float f0, f1, f2 = 0.f;
  if (lane < SCALAR) {
    f0 = xs[n * SCALAR + lane];
  } else {
    int tt = lane - SCALAR, tab = tt >> 5, d = tt & 31;  // tab 0 or 1
    const float* tp = tab == 0 ? t0 : t1;
    float sum = 0.f, cnt = 0.f;
#pragma unroll
    for (int l = 0; l < SEQ; ++l) {
      int id = sidx[w][tab * 20 + l];
      if (id != 0) { sum += tp[id * EMB + d]; cnt += 1.f; }
    }
    f0 = sum / (cnt + 1e-9f);
  }
  {
    int tt = 48 + lane, tab = tt >> 5, d = tt & 31;      // tab 1,2,3
    const float* tp = tab == 1 ? t1 : tab == 2 ? t2 : t3;
    float sum = 0.f, cnt = 0.f;
#pragma unroll
    for (int l = 0; l < SEQ; ++l) {
      int id = sidx[w][tab * 20 + l];
      if (id != 0) { sum += tp[id * EMB + d]; cnt += 1.f; }
    }
    f1 = sum / (cnt + 1e-9f);
  }
  if (l48) {
    int tt = 112 + lane, tab = tt >> 5, d = tt & 31;     // tab 3 or 4
    const float* tp = tab == 3 ? t3 : t4;
    float sum = 0.f, cnt = 0.f;
#pragma unroll
    for (int l = 0; l < SEQ; ++l) {
      int id = sidx[w][tab * 20 + l];
      if (id != 0) { sum += tp[id * EMB + d]; cnt += 1.f; }
    }
    f2 = sum / (cnt + 1e-9f);
  }
  float s = f0 + f1 + f2;  // f2==0 for lane>=48
  for (int off = 1; off < 64; off <<= 1) s += __shfl_xor(s, off);
  float mu = s / (float)IN_DIM;
  float v = (f0 - mu) * (f0 - mu) + (f1 - mu) * (f1 - mu) +
            (l48 ? (f2 - mu) * (f2 - mu) : 0.f);
  for (int off = 1; off < 64; off <<= 1) v += __shfl_xor(v, off);
  float rstd = 1.0f / sqrtf(v / (float)IN_DIM + 1e-5f);
  float hv0 = (f0 - mu) * rstd * gamma[lane] + beta[lane];
  float hv1 = (f1 - mu) * rstd * gamma[64 + lane] + beta[64 + lane];
  float hv2 = l48 ? (f2 - mu) * rstd * gamma[128 + lane] + beta[128 + lane] : 0.f;
  float* hr = hout + (size_t)n * IN_DIM;
  hr[lane] = hv0;
  hr[64 + lane] = hv1;
  if (l48) hr[128 + lane] = hv2;

  // Fused layer-1 attention logits: ps/pd[h] = h_row . was/wad[:,h]
  const float4* wsv = (const float4*)was4;
  const float4* wdv = (const float4*)wad4;
  float4 wsa = wsv[lane], wsb = wsv[64 + lane];
  float4 wsc = l48 ? wsv[128 + lane] : make_float4(0.f, 0.f, 0.f, 0.f);
  float4 wda = wdv[lane], wdb = wdv[64 + lane];
  float4 wdc = l48 ? wdv[128 + lane] : make_float4(0.f, 0.f, 0.f, 0.f);
  float ps0 = hv0 * wsa.x + hv1 * wsb.x + hv2 * wsc.x;
  float ps1 = hv0 * wsa.y + hv1 * wsb.y + hv2 * wsc.y;
  float ps2 = hv0 * wsa.z + hv1 * wsb.z + hv2 * wsc.z;
  float ps3 = hv0 * wsa.w + hv1 * wsb.w + hv2 * wsc.w;
  float pd0 = hv0 * wda.x + hv1 * wdb.x + hv2 * wdc.x;
  float pd1 = hv0 * wda.y + hv1 * wdb.y + hv2 * wdc.y;
  float pd2 = hv0 * wda.z + hv1 * wdb.z + hv2 * wdc.z;
  float pd3 = hv0 * wda.w + hv1 * wdb.w + hv2 * wdc.w;
  for (int off = 1; off < 64; off <<= 1) {
    ps0 += __shfl_xor(ps0, off); ps1 += __shfl_xor(ps1, off);
    ps2 += __shfl_xor(ps2, off); ps3 += __shfl_xor(ps3, off);
    pd0 += __shfl_xor(pd0, off); pd1 += __shfl_xor(pd1, off);
    pd2 += __shfl_xor(pd2, off); pd3 += __shfl_xor(pd3, off);
  }
  if (lane == 0) {
    *(float4*)&a_s[n * 4] = make_float4(ps0, ps1, ps2, ps3);
    *(float4*)&a_d[n * 4] = make_float4(pd0, pd1, pd2, pd3);
  }
}

// ---------------------------------------------------------------------------
// CSR build.
// ---------------------------------------------------------------------------
__global__ void count_kernel(const int* __restrict__ edge_index,
                             int* __restrict__ cnt, int E, int N) {
  int i = blockIdx.x * blockDim.x + threadIdx.x;
  if (i < E) {
    atomicAdd(&cnt[edge_index[E + i]], 1);
  } else if (i < E + N) {
    atomicAdd(&cnt[i - E], 1);  // self loop dst = node
  }
}

// 1024-thread single block: per-thread partial sums + Hillis-Steele scan of
// the 1024 partials (replaces the old 256-iteration serial t0 loop).
__global__ __launch_bounds__(1024) void prefix_kernel(const int* __restrict__ cnt,
                                                      int* __restrict__ indptr,
                                                      int n, int total) {
  __shared__ int ss[1024];
  int t = threadIdx.x;
  int per = (n + 1023) / 1024;
  int beg = t * per, end = min(beg + per, n);
  int s = 0;
  for (int i = beg; i < end; ++i) s += cnt[i];
  ss[t] = s;
  __syncthreads();
  for (int off = 1; off < 1024; off <<= 1) {
    int v = (t >= off) ? ss[t - off] : 0;
    __syncthreads();
    ss[t] += v;
    __syncthreads();
  }
  int run = ss[t] - s;  // exclusive prefix of this thread's range
  for (int i = beg; i < end; ++i) { indptr[i] = run; run += cnt[i]; }
  if (t == 0) indptr[n] = total;
}

__global__ void scatter_kernel(const int* __restrict__ edge_index,
                               const int* __restrict__ indptr,
                               int* __restrict__ cursor,
                               int* __restrict__ srcs, int E, int N) {
  int i = blockIdx.x * blockDim.x + threadIdx.x;
  int s, d;
  if (i < E) { s = edge_index[i]; d = edge_index[E + i]; }
  else if (i < E + N) { s = i - E; d = s; }
  else return;
  int pos = indptr[d] + atomicAdd(&cursor[d], 1);
  srcs[pos] = s;
}

// ---------------------------------------------------------------------------
// Layer-1 softmax + aggregate h (176-dim) per head -> aggh[(ln*4+h)*176+k].
// (Aggregate in the SMALL dim first — round-5's GEMM-first variant tripled
// gather traffic, 318MB FETCH. Keep this order.)
// ---------------------------------------------------------------------------
__global__ __launch_bounds__(256) void agg1h_kernel(
    const float* __restrict__ h, const float* __restrict__ a_src,
    const float* __restrict__ a_dst, const int* __restrict__ indptr,
    const int* __restrict__ srcs, float* __restrict__ aggh,
    int n0, int nM) {
  int lane = threadIdx.x & 63;
  int ln = blockIdx.x * 4 + (threadIdx.x >> 6);
  if (ln >= nM) return;
  int n = n0 + ln;
  int beg = indptr[n], end = indptr[n + 1];
  int deg = end - beg;
  float4 ad = *(const float4*)&a_dst[n * 4];
  bool l48 = lane < 48;
  float acc[4][3] = {};

  auto body = [&](int s, float al0, float al1, float al2, float al3) {
    const float* r = h + (size_t)s * IN_DIM;
    float v0 = r[lane];
    float v1 = r[64 + lane];
    float v2 = l48 ? r[128 + lane] : 0.f;
    acc[0][0] += al0 * v0; acc[0][1] += al0 * v1; acc[0][2] += al0 * v2;
    acc[1][0] += al1 * v0; acc[1][1] += al1 * v1; acc[1][2] += al1 * v2;
    acc[2][0] += al2 * v0; acc[2][1] += al2 * v1; acc[2][2] += al2 * v2;
    acc[3][0] += al3 * v0; acc[3][1] += al3 * v1; acc[3][2] += al3 * v2;
  };

  if (deg <= 64) {
    int j = beg + lane;
    int s = 0;
    float e0 = -INFINITY, e1 = -INFINITY, e2 = -INFINITY, e3 = -INFINITY;
    if (j < end) {
      s = srcs[j];
      float4 as = *(const float4*)&a_src[s * 4];
      e0 = leaky(as.x + ad.x); e1 = leaky(as.y + ad.y);
      e2 = leaky(as.z + ad.z); e3 = leaky(as.w + ad.w);
    }
    float m0 = e0, m1 = e1, m2 = e2, m3 = e3;
    for (int off = 1; off < 64; off <<= 1) {
      m0 = fmaxf(m0, __shfl_xor(m0, off)); m1 = fmaxf(m1, __shfl_xor(m1, off));
      m2 = fmaxf(m2, __shfl_xor(m2, off)); m3 = fmaxf(m3, __shfl_xor(m3, off));
    }
    float x0 = (j < end) ? expf(e0 - m0) : 0.f;
    float x1 = (j < end) ? expf(e1 - m1) : 0.f;
    float x2 = (j < end) ? expf(e2 - m2) : 0.f;
    float x3 = (j < end) ? expf(e3 - m3) : 0.f;
    float d0 = x0, d1 = x1, d2 = x2, d3 = x3;
    for (int off = 1; off < 64; off <<= 1) {
      d0 += __shfl_xor(d0, off); d1 += __shfl_xor(d1, off);
      d2 += __shfl_xor(d2, off); d3 += __shfl_xor(d3, off);
    }
    float al0 = x0 / (d0 + 1e-16f), al1 = x1 / (d1 + 1e-16f);
    float al2 = x2 / (d2 + 1e-16f), al3 = x3 / (d3 + 1e-16f);
    int jj = 0;
    for (; jj + 2 <= deg; jj += 2) {
      int sa = readlane_i(s, jj), sb = readlane_i(s, jj + 1);
      float a0 = readlane_f(al0, jj), a1 = readlane_f(al1, jj);
      float a2 = readlane_f(al2, jj), a3 = readlane_f(al3, jj);
      float b0 = readlane_f(al0, jj + 1), b1 = readlane_f(al1, jj + 1);
      float b2 = readlane_f(al2, jj + 1), b3 = readlane_f(al3, jj + 1);
      body(sa, a0, a1, a2, a3);
      body(sb, b0, b1, b2, b3);
    }
    if (jj < deg) {
      int sa = readlane_i(s, jj);
      body(sa, readlane_f(al0, jj), readlane_f(al1, jj),
           readlane_f(al2, jj), readlane_f(al3, jj));
    }
  } else {
    float m0 = -INFINITY, m1 = -INFINITY, m2 = -INFINITY, m3 = -INFINITY;
    for (int j0 = beg; j0 < end; j0 += 64) {
      int j = j0 + lane;
      if (j < end) {
        int s = srcs[j];
        float4 as = *(const float4*)&a_src[s * 4];
        m0 = fmaxf(m0, leaky(as.x + ad.x)); m1 = fmaxf(m1, leaky(as.y + ad.y));
        m2 = fmaxf(m2, leaky(as.z + ad.z)); m3 = fmaxf(m3, leaky(as.w + ad.w));
      }
    }
    for (int off = 1; off < 64; off <<= 1) {
      m0 = fmaxf(m0, __shfl_xor(m0, off)); m1 = fmaxf(m1, __shfl_xor(m1, off));
      m2 = fmaxf(m2, __shfl_xor(m2, off)); m3 = fmaxf(m3, __shfl_xor(m3, off));
    }
    float d0 = 0.f, d1 = 0.f, d2 = 0.f, d3 = 0.f;
    for (int j0 = beg; j0 < end; j0 += 64) {
      int j = j0 + lane;
      if (j < end) {
        int s = srcs[j];
        float4 as = *(const float4*)&a_src[s * 4];
        d0 += expf(leaky(as.x + ad.x) - m0); d1 += expf(leaky(as.y + ad.y) - m1);
        d2 += expf(leaky(as.z + ad.z) - m2); d3 += expf(leaky(as.w + ad.w) - m3);
      }
    }
    for (int off = 1; off < 64; off <<= 1) {
      d0 += __shfl_xor(d0, off); d1 += __shfl_xor(d1, off);
      d2 += __shfl_xor(d2, off); d3 += __shfl_xor(d3, off);
    }
    float r0 = 1.f / (d0 + 1e-16f), r1 = 1.f / (d1 + 1e-16f);
    float r2 = 1.f / (d2 + 1e-16f), r3 = 1.f / (d3 + 1e-16f);
    for (int j0 = beg; j0 < end; j0 += 64) {
      int jn = min(64, end - j0);
      int j = j0 + lane;
      int s = 0;
      float al0 = 0.f, al1 = 0.f, al2 = 0.f, al3 = 0.f;
      if (j < end) {
        s = srcs[j];
        float4 as = *(const float4*)&a_src[s * 4];
        al0 = expf(leaky(as.x + ad.x) - m0) * r0;
        al1 = expf(leaky(as.y + ad.y) - m1) * r1;
        al2 = expf(leaky(as.z + ad.z) - m2) * r2;
        al3 = expf(leaky(as.w + ad.w) - m3) * r3;
      }
      for (int jj = 0; jj < jn; ++jj) {
        body(readlane_i(s, jj), readlane_f(al0, jj), readlane_f(al1, jj),
             readlane_f(al2, jj), readlane_f(al3, jj));
      }
    }
  }

  size_t base = (size_t)ln * (4 * IN_DIM);
#pragma unroll
  for (int hh = 0; hh < 4; ++hh) {
    aggh[base + hh * IN_DIM + lane] = acc[hh][0];
    aggh[base + hh * IN_DIM + 64 + lane] = acc[hh][1];
    if (l48) aggh[base + hh * IN_DIM + 128 + lane] = acc[hh][2];
  }
}

// ---------------------------------------------------------------------------
// Head-GEMM via f16 hi/lo MFMA (3-product fp32 emulation). LDS-free, no
// barriers. Wave tile SHRUNK to 16 rows x 64 cols (was 32x64): halves AGPR
// pressure (acc 8x f32x4 instead of 16) and doubles wave count to 10000 —
// round-3 counters showed Occupancy 15.5% with nothing saturated
// (latency-bound). wid = (rg*4+hh)*2+colhalf.
// K padded to 192: tail ks clamps A k-offset in-row; B zeros kill it.
// f32 stores (f16 stores inflated WRITE_SIZE 40->72MB in round 4).
// ---------------------------------------------------------------------------
__global__ __launch_bounds__(256) void gemm_head_mfma_kernel(
    const float* __restrict__ aggh, const half8v* __restrict__ PBh,
    const half8v* __restrict__ PBl, const float* __restrict__ b1,
    float* __restrict__ out1, int M, int n0) {
  int lane = threadIdx.x & 63;
  int wid = (blockIdx.x * 256 + threadIdx.x) >> 6;
  int colhalf = wid & 1;
  int hh = (wid >> 1) & 3;
  int rg = wid >> 3;
  int rows0 = rg * 16;
  if (rows0 >= M) return;
  int r = lane & 15, g = lane >> 4;
  f32x4 acc[4] = {};
  f32x4 accm[4] = {};
  const float* a0 = aggh + ((size_t)(rows0 + r) * 4 + hh) * IN_DIM;
#pragma unroll 2
  for (int ks = 0; ks < 6; ++ks) {
    int kg = ks * 32 + g * 8;
    int koff = (kg + 8 <= IN_DIM) ? kg : 0;  // clamp tail in-row (B zeros kill it)
    const float* ap = a0 + koff;
    float av[8];
    *(float4*)&av[0] = *(const float4*)(ap);
    *(float4*)&av[4] = *(const float4*)(ap + 4);
    half8v ah, al;
#pragma unroll
    for (int j = 0; j < 8; ++j) {
      _Float16 hv = (_Float16)av[j];
      ah[j] = hv;
      al[j] = (_Float16)((av[j] - (float)hv) * LO_SCALE);
    }
    const half8v* bh = PBh + (size_t)(((hh * 6 + ks) * 8 + colhalf * 4) * 64) + lane;
    const half8v* bl = PBl + (size_t)(((hh * 6 + ks) * 8 + colhalf * 4) * 64) + lane;
#pragma unroll
    for (int nt = 0; nt < 4; ++nt) {
      half8v bhv = bh[nt * 64], blv = bl[nt * 64];
      accm[nt] = __builtin_amdgcn_mfma_f32_16x16x32_f16(al, bhv, accm[nt], 0, 0, 0);
      accm[nt] = __builtin_amdgcn_mfma_f32_16x16x32_f16(ah, blv, accm[nt], 0, 0, 0);
      acc[nt]  = __builtin_amdgcn_mfma_f32_16x16x32_f16(ah, bhv, acc[nt], 0, 0, 0);
    }
  }
#pragma unroll
  for (int nt = 0; nt < 4; ++nt) {
    int col = hh * 128 + colhalf * 64 + nt * 16 + r;
    float bb = b1[col];
#pragma unroll
    for (int i = 0; i < 4; ++i) {
      int row = rows0 + g * 4 + i;
      if (row < M)
        out1[(size_t)(n0 + row) * 512 + col] =
            elu(acc[nt][i] + accm[nt][i] * LO_INV + bb);
    }
  }
}

// ---------------------------------------------------------------------------
// GEMM2 (out1@W2) via f16 hi/lo MFMA + fused layer-2 att logits.
// Wave tile shrunk to 16 rows x 32 cols (was 16x64): doubles wave count to
// 5000 (was 2500 = 2.4/SIMD, grid-starved). wid = rg*4 + colq.
// a2s/a2d: per-row partial dot, 16-lane shfl reduce + 1 atomic per
// (row, colq) into pre-zeroed buffers.
// ---------------------------------------------------------------------------
__global__ __launch_bounds__(256) void gemm2att_mfma_kernel(
    const float* __restrict__ A, const half8v* __restrict__ PBh,
    const half8v* __restrict__ PBl, const float* __restrict__ att_s,
    const float* __restrict__ att_d, float* __restrict__ C,
    float* __restrict__ a_s, float* __restrict__ a_d, int M) {
  int lane = threadIdx.x & 63;
  int wid = (blockIdx.x * 256 + threadIdx.x) >> 6;
  int colq = wid & 3;
  int rg = wid >> 2;
  int row0 = rg * 16;
  if (row0 >= M) return;
  int r = lane & 15, g = lane >> 4;
  const float* arow = A + (size_t)(row0 + r) * 512 + g * 8;
  f32x4 acc[2] = {};
  f32x4 accm[2] = {};
#pragma unroll 2
  for (int ks = 0; ks < 16; ++ks) {
    float av[8];
    *(float4*)&av[0] = *(const float4*)(arow + ks * 32);
    *(float4*)&av[4] = *(const float4*)(arow + ks * 32 + 4);
    half8v ah, al;
#pragma unroll
    for (int j = 0; j < 8; ++j) {
      _Float16 hv = (_Float16)av[j];
      ah[j] = hv;
      al[j] = (_Float16)((av[j] - (float)hv) * LO_SCALE);
    }
    const half8v* bh = PBh + (size_t)((ks * 8 + colq * 2) * 64) + lane;
    const half8v* bl = PBl + (size_t)((ks * 8 + colq * 2) * 64) + lane;
#pragma unroll
    for (int nt = 0; nt < 2; ++nt) {
      half8v bhv = bh[nt * 64], blv = bl[nt * 64];
      accm[nt] = __builtin_amdgcn_mfma_f32_16x16x32_f16(al, bhv, accm[nt], 0, 0, 0);
      accm[nt] = __builtin_amdgcn_mfma_f32_16x16x32_f16(ah, blv, accm[nt], 0, 0, 0);
      acc[nt]  = __builtin_amdgcn_mfma_f32_16x16x32_f16(ah, bhv, acc[nt], 0, 0, 0);
    }
  }
  float ps[4] = {0.f, 0.f, 0.f, 0.f}, pd[4] = {0.f, 0.f, 0.f, 0.f};
#pragma unroll
  for (int nt = 0; nt < 2; ++nt) {
    int col = colq * 32 + nt * 16 + r;
    float as_ = att_s[col], ad_ = att_d[col];
#pragma unroll
    for (int i = 0; i < 4; ++i) {
      float v = acc[nt][i] + accm[nt][i] * LO_INV;
      int row = row0 + g * 4 + i;
      C[(size_t)row * 128 + col] = v;
      ps[i] += v * as_;
      pd[i] += v * ad_;
    }
  }
#pragma unroll
  for (int i = 0; i < 4; ++i) {
    for (int off = 1; off < 16; off <<= 1) {
      ps[i] += __shfl_xor(ps[i], off);
      pd[i] += __shfl_xor(pd[i], off);
    }
  }
  if (r == 0) {
#pragma unroll
    for (int i = 0; i < 4; ++i) {
      atomicAdd(&a_s[row0 + g * 4 + i], ps[i]);
      atomicAdd(&a_d[row0 + g * 4 + i], pd[i]);
    }
  }
}

// ---------------------------------------------------------------------------
// Layer-2 aggregate: H=1, C=128. Half-wave per edge, float4 loads.
// ---------------------------------------------------------------------------
__global__ __launch_bounds__(256) void agg2_kernel(
    const float* __restrict__ xw, const float* __restrict__ a_src,
    const float* __restrict__ a_dst, const int* __restrict__ indptr,
    const int* __restrict__ srcs, const float* __restrict__ bias,
    float* __restrict__ out) {
  int lane = threadIdx.x & 63;
  int n = blockIdx.x * 4 + (threadIdx.x >> 6);
  if (n >= N_NODES) return;
  int beg = indptr[n], end = indptr[n + 1];
  int deg = end - beg;
  float adn = a_dst[n];
  int half = lane >> 5, l32 = lane & 31;
  float4 acc = make_float4(0.f, 0.f, 0.f, 0.f);

  auto pairs = [&](int s, float al, int jn) {
    int jj = 0;
    for (; jj + 2 <= jn; jj += 2) {
      int sa = readlane_i(s, jj), sb = readlane_i(s, jj + 1);
      float aa = readlane_f(al, jj), ab = readlane_f(al, jj + 1);
      int sh = half ? sb : sa;
      float ahx = half ? ab : aa;
      float4 v = *(const float4*)&xw[(size_t)sh * HID + l32 * 4];
      acc.x += ahx * v.x; acc.y += ahx * v.y; acc.z += ahx * v.z; acc.w += ahx * v.w;
    }
    if (jj < jn) {
      int sa = readlane_i(s, jj);
      float ahx = half ? 0.f : readlane_f(al, jj);
      float4 v = *(const float4*)&xw[(size_t)sa * HID + l32 * 4];
      acc.x += ahx * v.x; acc.y += ahx * v.y; acc.z += ahx * v.z; acc.w += ahx * v.w;
    }
  };

  if (deg <= 64) {
    int j = beg + lane;
    int s = 0;
    float e = -INFINITY;
    if (j < end) { s = srcs[j]; e = leaky(a_src[s] + adn); }
    float m = e;
    for (int off = 1; off < 64; off <<= 1) m = fmaxf(m, __shfl_xor(m, off));
    float x = (j < end) ? expf(e - m) : 0.f;
    float d = x;
    for (int off = 1; off < 64; off <<= 1) d += __shfl_xor(d, off);
    float al = x / (d + 1e-16f);
    pairs(s, al, deg);
  } else {
    float m = -INFINITY;
    for (int j0 = beg; j0 < end; j0 += 64) {
      int j = j0 + lane;
      if (j < end) m = fmaxf(m, leaky(a_src[srcs[j]] + adn));
    }
    for (int off = 1; off < 64; off <<= 1) m = fmaxf(m, __shfl_xor(m, off));
    float d = 0.f;
    for (int j0 = beg; j0 < end; j0 += 64) {
      int j = j0 + lane;
      if (j < end) d += expf(leaky(a_src[srcs[j]] + adn) - m);
    }
    for (int off = 1; off < 64; off <<= 1) d += __shfl_xor(d, off);
    float rd = 1.f / (d + 1e-16f);
    for (int j0 = beg; j0 < end; j0 += 64) {
      int jn = min(64, end - j0);
      int j = j0 + lane;
      int s = 0;
      float al = 0.f;
      if (j < end) {
        s = srcs[j];
        al = expf(leaky(a_src[s] + adn) - m) * rd;
      }
      pairs(s, al, jn);
    }
  }

  acc.x += __shfl_xor(acc.x, 32); acc.y += __shfl_xor(acc.y, 32);
  acc.z += __shfl_xor(acc.z, 32); acc.w += __shfl_xor(acc.w, 32);
  if (half == 0) {
    float4 b = *(const float4*)&bias[l32 * 4];
    float4 o;
    o.x = elu(acc.x + b.x); o.y = elu(acc.y + b.y);
    o.z = elu(acc.z + b.z); o.w = elu(acc.w + b.w);
    *(float4*)&out[(size_t)n * HID + l32 * 4] = o;
  }
}

// ---------------------------------------------------------------------------
// Graph ranges (batch sorted), two-stage max-pool per graph, classifier head.
// ---------------------------------------------------------------------------
__global__ void gstart_kernel(const int* __restrict__ batch,
                              int* __restrict__ gstarts, int N, int G) {
  int t = threadIdx.x;
  if (t > G) return;
  int lo = 0, hi = N;
  while (lo < hi) {
    int mid = (lo + hi) >> 1;
    if (batch[mid] < t) lo = mid + 1; else hi = mid;
  }
  gstarts[t] = lo;
}

__global__ __launch_bounds__(HID) void pool_part_kernel(
    const float* __restrict__ out2, const int* __restrict__ gstarts,
    float* __restrict__ part) {
  int g = blockIdx.x, s = blockIdx.y, t = threadIdx.x;
  int beg = gstarts[g], end = gstarts[g + 1];
  int len = end - beg;
  int b0 = beg + (int)(((long long)len * s) / POOL_SLICES);
  int b1 = beg + (int)(((long long)len * (s + 1)) / POOL_SLICES);
  float m = -INFINITY;
  for (int n = b0; n < b1; ++n) m = fmaxf(m, out2[(size_t)n * HID + t]);
  part[((size_t)g * POOL_SLICES + s) * HID + t] = m;
}

__global__ __launch_bounds__(HID) void pool_reduce_kernel(
    const float* __restrict__ part, float* __restrict__ pooled) {
  int g = blockIdx.x, t = threadIdx.x;
  float m = -INFINITY;
#pragma unroll
  for (int s = 0; s < POOL_SLICES; ++s)
    m = fmaxf(m, part[((size_t)g * POOL_SLICES + s) * HID + t]);
  pooled[g * HID + t] = m;
}

__global__ __launch_bounds__(HID) void cls_kernel(const float* __restrict__ pooled,
                                                  const float* __restrict__ w1,
                                                  const float* __restrict__ b1,
                                                  const float* __restrict__ w2,
                                                  const float* __restrict__ b2,
                                                  float* __restrict__ out) {
  int g = blockIdx.x, t = threadIdx.x;
  __shared__ float sp[HID], sh1[HID / 2];
  sp[t] = pooled[g * HID + t];
  __syncthreads();
  if (t < HID / 2) {
    float s = b1[t];
    for (int k = 0; k < HID; ++k) s += sp[k] * w1[k * (HID / 2) + t];
    sh1[t] = fmaxf(s, 0.f);
  }
  __syncthreads();
  if (t < 2) {
    float o = b2[t];
    for (int k = 0; k < HID / 2; ++k) o += sh1[k] * w2[k * 2 + t];
    out[g * 2 + t] = o;
  }
}

// ---------------------------------------------------------------------------
extern "C" void kernel_launch(void* const* d_in, const int* in_sizes, int n_in,
                              void* d_out, int out_size, void* d_ws, size_t ws_size,
                              hipStream_t stream) {
  const float* x_scalar = (const float*)d_in[0];
  const int* x_opcode   = (const int*)d_in[1];
  const int* x_source   = (const int*)d_in[2];
  const int* x_sink     = (const int*)d_in[3];
  const int* x_string   = (const int*)d_in[4];
  const int* x_payload  = (const int*)d_in[5];
  const int* edge_index = (const int*)d_in[6];
  const int* batch      = (const int*)d_in[7];
  const float* emb_opcode = (const float*)d_in[8];
  const float* emb_source = (const float*)d_in[9];
  const float* emb_sink   = (const float*)d_in[10];
  const float* emb_string = (const float*)d_in[11];
  const float* emb_payload= (const float*)d_in[12];
  const float* ln_gamma = (const float*)d_in[13];
  const float* ln_beta  = (const float*)d_in[14];
  const float* W1       = (const float*)d_in[15];
  const float* att_src1 = (const float*)d_in[16];
  const float* att_dst1 = (const float*)d_in[17];
  const float* b1       = (const float*)d_in[18];
  const float* W2       = (const float*)d_in[19];
  const float* att_src2 = (const float*)d_in[20];
  const float* att_dst2 = (const float*)d_in[21];
  const float* b2       = (const float*)d_in[22];
  const float* cls_w1   = (const float*)d_in[23];
  const float* cls_b1   = (const float*)d_in[24];
  const float* cls_w2   = (const float*)d_in[25];
  const float* cls_b2   = (const float*)d_in[26];

  // Adaptive chunk: run layer-1 agg + head-GEMM in 1 pass if workspace allows.
  auto total_bytes = [&](int chunk) -> size_t {
    size_t f = (size_t)N_NODES * IN_DIM + (size_t)chunk * 4 * IN_DIM +
               (size_t)N_NODES * 512 + (size_t)N_NODES * HID +
               N_NODES * 4 * 2 + N_NODES * 2 + IN_DIM * 4 * 2 + N_GRAPHS * HID;
    size_t ii = (N_NODES + 1) + N_NODES * 2 + TOT_EDGES + (N_GRAPHS + 1);
    size_t f16b = (size_t)2 * (PB2_ELEMS + PB1_ELEMS) * sizeof(_Float16) + 32;
    size_t poolb = (size_t)N_GRAPHS * POOL_SLICES * HID * 4 + 32;
    return f * 4 + ii * 4 + f16b + poolb + 256;
  };
  int chunk = (ws_size >= total_bytes(N_NODES)) ? N_NODES : CHUNK_SMALL;

  float* h      = (float*)d_ws;                        // [N,176]
  float* aggh   = h + (size_t)N_NODES * IN_DIM;        // [chunk*704]
  float* out1   = aggh + (size_t)chunk * 4 * IN_DIM;   // [N,512]
  float* out2   = out1 + (size_t)N_NODES * 512;        // [N,128]
  float* a1s    = out2 + (size_t)N_NODES * HID;        // [N,4]
  float* a1d    = a1s + N_NODES * 4;
  float* was4   = a1d + N_NODES * 4;                   // [176*4]
  float* wad4   = was4 + IN_DIM * 4;                   // [176*4]
  float* pooled = wad4 + IN_DIM * 4;                   // [G,128]
  int* indptr = (int*)(pooled + N_GRAPHS * HID);       // [N+1]
  int* cnt    = indptr + (N_NODES + 1);                // [N]   (zeroed)
  int* cursor = cnt + N_NODES;                         // [N]   (zeroed)
  float* a2s  = (float*)(cursor + N_NODES);            // [N]   (zeroed)
  float* a2d  = a2s + N_NODES;                         // [N]   (zeroed)
  int* srcs   = (int*)(a2d + N_NODES);                 // [E+N]
  int* gstarts= srcs + TOT_EDGES;                      // [G+1]
  // f16 pack buffers, 16B-aligned (half8v loads)
  uintptr_t pal = ((uintptr_t)(gstarts + N_GRAPHS + 1) + 15) & ~(uintptr_t)15;
  _Float16* PB2h = (_Float16*)pal;                     // [65536]
  _Float16* PB2l = PB2h + PB2_ELEMS;                   // [65536]
  _Float16* PB1h = PB2l + PB2_ELEMS;                   // [98304]
  _Float16* PB1l = PB1h + PB1_ELEMS;                   // [98304]
  uintptr_t ppal = ((uintptr_t)(PB1l + PB1_ELEMS) + 15) & ~(uintptr_t)15;
  float* pool_part = (float*)ppal;                     // [G*32*128]
  float* xw2  = h;  // alias: h dead after last agg1h; xw2 [N,128] fits in h [N,176]

  // zero cnt, cursor, a2s, a2d in one shot (contiguous)
  hipMemsetAsync(cnt, 0, 4 * N_NODES * sizeof(int), stream);

  const int NB4 = (N_NODES + 3) / 4;

  // setup: wasd + pack_w1 + pack_w2 in one launch (inputs only).
  setup_kernel<<<124, 256, 0, stream>>>(W1, att_src1, att_dst1, W2,
                                        was4, wad4, PB1h, PB1l, PB2h, PB2l);

  feats_ln_kernel<<<NB4, 256, 0, stream>>>(
      x_scalar, x_opcode, x_source, x_sink, x_string, x_payload,
      emb_opcode, emb_source, emb_sink, emb_string, emb_payload,
      ln_gamma, ln_beta, was4, wad4, h, a1s, a1d);

  int nthreads = TOT_EDGES;
  count_kernel<<<(nthreads + 255) / 256, 256, 0, stream>>>(edge_index, cnt, N_EDGES, N_NODES);
  prefix_kernel<<<1, 1024, 0, stream>>>(cnt, indptr, N_NODES, TOT_EDGES);
  scatter_kernel<<<(nthreads + 255) / 256, 256, 0, stream>>>(edge_index, indptr, cursor, srcs, N_EDGES, N_NODES);

  for (int n0 = 0; n0 < N_NODES; n0 += chunk) {
    int nM = min(chunk, N_NODES - n0);
    agg1h_kernel<<<(nM + 3) / 4, 256, 0, stream>>>(h, a1s, a1d, indptr, srcs, aggh, n0, nM);
    int rgs = (nM + 15) / 16;           // 16 rows per wave
    gemm_head_mfma_kernel<<<rgs * 2, 256, 0, stream>>>(   // rgs*8 waves / 4 per block
        aggh, (const half8v*)PB1h, (const half8v*)PB1l, b1, out1, nM, n0);
  }

  // GEMM2 + fused att2 logits via MFMA: 5000 waves = 1250 blocks.
  gemm2att_mfma_kernel<<<(N_NODES + 15) / 16, 256, 0, stream>>>(
      out1, (const half8v*)PB2h, (const half8v*)PB2l, att_src2, att_dst2,
      xw2, a2s, a2d, N_NODES);

  agg2_kernel<<<NB4, 256, 0, stream>>>(xw2, a2s, a2d, indptr, srcs, b2, out2);

  gstart_kernel<<<1, 128, 0, stream>>>(batch, gstarts, N_NODES, N_GRAPHS);
  pool_part_kernel<<<dim3(N_GRAPHS, POOL_SLICES), HID, 0, stream>>>(out2, gstarts, pool_part);
  pool_reduce_kernel<<<N_GRAPHS, HID, 0, stream>>>(pool_part, pooled);
  cls_kernel<<<N_GRAPHS, HID, 0, stream>>>(pooled, cls_w1, cls_b1, cls_w2, cls_b2, (float*)d_out);
}

// Round 8
// 368.002 us; speedup vs baseline: 1.1875x; 1.0381x over previous
//
#include <hip/hip_runtime.h>
#include <hip/hip_bf16.h>
#include <math.h>

// Problem constants (match reference setup_inputs()).
#define N_NODES 20000
#define N_EDGES 320000
#define N_GRAPHS 64
#define SEQ 20
#define SCALAR 16
#define EMB 32
#define HID 128
#define IN_DIM 176         // SCALAR + 5*EMB
#define TOT_EDGES (N_EDGES + N_NODES)  // with self loops
#define CHUNK_SMALL 10000  // fallback node chunk when workspace is tight
#define POOL_SLICES 32     // parallel slices per graph for max-pool

// f16 MFMA types
typedef _Float16 half8v __attribute__((ext_vector_type(8)));
typedef float f32x4 __attribute__((ext_vector_type(4)));
#define LO_SCALE 2048.0f
#define LO_INV (1.0f / 2048.0f)

// Pack-buffer element counts (f16 elems each, hi and lo separately)
#define PB2_ELEMS (16 * 8 * 64 * 8)      // [ks16][ntile8][lane64][j8] = 65536
#define PB1_ELEMS (4 * 6 * 8 * 64 * 8)   // [head4][ks6][ntile8][lane64][j8] = 98304

// Grid split constants for the fused launches.
#define SETUP_BLOCKS 124                      // 44 wasd + 48 pack_w1 + 32 pack_w2
#define COUNT_BLOCKS ((TOT_EDGES + 255) / 256)  // 1329
#define NB4 ((N_NODES + 3) / 4)               // 5000 feats blocks

__device__ inline float readlane_f(float v, int l) {
  return __uint_as_float(__builtin_amdgcn_readlane(__float_as_uint(v), l));
}
__device__ inline int readlane_i(int v, int l) {
  return __builtin_amdgcn_readlane(v, l);
}
__device__ inline float leaky(float e) { return e >= 0.f ? e : 0.2f * e; }
__device__ inline float elu(float v) { return v > 0.f ? v : expf(v) - 1.f; }

// ---------------------------------------------------------------------------
// LAUNCH 1 (fused, all parts read ONLY kernel inputs + pre-zeroed cnt):
//   blocks [0,44):    wasd precompute
//   blocks [44,92):   pack_w1
//   blocks [92,124):  pack_w2
//   blocks [124,124+COUNT_BLOCKS): CSR degree count
//   last block:       gstart binary search
// Independent outputs -> safe under undefined dispatch order.
// ---------------------------------------------------------------------------
__global__ __launch_bounds__(256) void setup_count_kernel(
    const float* __restrict__ W1, const float* __restrict__ att_s1,
    const float* __restrict__ att_d1, const float* __restrict__ W2,
    const int* __restrict__ edge_index, const int* __restrict__ batch,
    float* __restrict__ was4, float* __restrict__ wad4,
    _Float16* __restrict__ PB1h, _Float16* __restrict__ PB1l,
    _Float16* __restrict__ PB2h, _Float16* __restrict__ PB2l,
    int* __restrict__ cnt, int* __restrict__ gstarts) {
  int b = blockIdx.x;
  if (b < 44) {
    // wasd: was/wad[k][h] = sum_c W1[k, h*128+c] * att[h*128+c]
    int lane = threadIdx.x & 63;
    int k = b * 4 + (threadIdx.x >> 6);
    if (k >= IN_DIM) return;
    const float* wrow = W1 + (size_t)k * 512;
    float s[4], d[4];
#pragma unroll
    for (int hh = 0; hh < 4; ++hh) {
      float w0 = wrow[hh * 128 + lane], w1 = wrow[hh * 128 + 64 + lane];
      float a0 = att_s1[hh * 128 + lane], a1 = att_s1[hh * 128 + 64 + lane];
      float c0 = att_d1[hh * 128 + lane], c1 = att_d1[hh * 128 + 64 + lane];
      s[hh] = w0 * a0 + w1 * a1;
      d[hh] = w0 * c0 + w1 * c1;
    }
    for (int off = 1; off < 64; off <<= 1) {
#pragma unroll
      for (int hh = 0; hh < 4; ++hh) {
        s[hh] += __shfl_xor(s[hh], off);
        d[hh] += __shfl_xor(d[hh], off);
      }
    }
    if (lane == 0) {
      *(float4*)&was4[k * 4] = make_float4(s[0], s[1], s[2], s[3]);
      *(float4*)&wad4[k * 4] = make_float4(d[0], d[1], d[2], d[3]);
    }
  } else if (b < 92) {
    // pack_w1: [hh4][ks6][ntile8][lane64][j8], K zero-padded to 192.
    int t = (b - 44) * 256 + threadIdx.x;  // 12288 threads exactly
    int lane = t & 63, wi = t >> 6;
    int r = lane & 15, g = lane >> 4;
    int ntile = wi & 7, rem = wi >> 3;
    int ks = rem % 6, hh = rem / 6;
    int col = hh * 128 + ntile * 16 + r;
    size_t o = ((size_t)wi * 64 + lane) * 8;
#pragma unroll
    for (int j = 0; j < 8; ++j) {
      int k = ks * 32 + g * 8 + j;
      float v = (k < IN_DIM) ? W1[(size_t)k * 512 + col] : 0.f;
      _Float16 h = (_Float16)v;
      PB1h[o + j] = h;
      PB1l[o + j] = (_Float16)((v - (float)h) * LO_SCALE);
    }
  } else if (b < SETUP_BLOCKS) {
    // pack_w2: [ks16][ntile8][lane64][j8]
    int t = (b - 92) * 256 + threadIdx.x;  // 8192 threads exactly
    int lane = t & 63, wi = t >> 6;
    int r = lane & 15, g = lane >> 4;
    int ks = wi >> 3, ntile = wi & 7;
    int col = ntile * 16 + r;
    size_t o = ((size_t)wi * 64 + lane) * 8;
#pragma unroll
    for (int j = 0; j < 8; ++j) {
      int k = ks * 32 + g * 8 + j;
      float v = W2[(size_t)k * 128 + col];
      _Float16 h = (_Float16)v;
      PB2h[o + j] = h;
      PB2l[o + j] = (_Float16)((v - (float)h) * LO_SCALE);
    }
  } else if (b < SETUP_BLOCKS + COUNT_BLOCKS) {
    // CSR degree count (cnt pre-zeroed by memset).
    int i = (b - SETUP_BLOCKS) * 256 + threadIdx.x;
    if (i < N_EDGES) {
      atomicAdd(&cnt[edge_index[N_EDGES + i]], 1);
    } else if (i < TOT_EDGES) {
      atomicAdd(&cnt[i - N_EDGES], 1);  // self loop dst = node
    }
  } else {
    // gstart: binary search graph boundaries in sorted batch.
    int t = threadIdx.x;
    if (t > N_GRAPHS) return;
    int lo = 0, hi = N_NODES;
    while (lo < hi) {
      int mid = (lo + hi) >> 1;
      if (batch[mid] < t) lo = mid + 1; else hi = mid;
    }
    gstarts[t] = lo;
  }
}

// ---------------------------------------------------------------------------
// 1024-thread single block: per-thread partial sums + Hillis-Steele scan.
// ---------------------------------------------------------------------------
__global__ __launch_bounds__(1024) void prefix_kernel(const int* __restrict__ cnt,
                                                      int* __restrict__ indptr,
                                                      int n, int total) {
  __shared__ int ss[1024];
  int t = threadIdx.x;
  int per = (n + 1023) / 1024;
  int beg = t * per, end = min(beg + per, n);
  int s = 0;
  for (int i = beg; i < end; ++i) s += cnt[i];
  ss[t] = s;
  __syncthreads();
  for (int off = 1; off < 1024; off <<= 1) {
    int v = (t >= off) ? ss[t - off] : 0;
    __syncthreads();
    ss[t] += v;
    __syncthreads();
  }
  int run = ss[t] - s;  // exclusive prefix of this thread's range
  for (int i = beg; i < end; ++i) { indptr[i] = run; run += cnt[i]; }
  if (t == 0) indptr[n] = total;
}

// ---------------------------------------------------------------------------
// LAUNCH 3 (fused): blocks [0, COUNT_BLOCKS): CSR scatter (needs prefix);
// blocks [COUNT_BLOCKS, COUNT_BLOCKS+NB4): feats+LN+att1 (needs setup).
// Disjoint outputs; scatter first so its short blocks drain under feats.
// ---------------------------------------------------------------------------
__global__ __launch_bounds__(256) void scatter_feats_kernel(
    const int* __restrict__ edge_index, const int* __restrict__ indptr,
    int* __restrict__ cursor, int* __restrict__ srcs,
    const float* __restrict__ xs,
    const int* __restrict__ i0, const int* __restrict__ i1,
    const int* __restrict__ i2, const int* __restrict__ i3,
    const int* __restrict__ i4,
    const float* __restrict__ t0, const float* __restrict__ t1,
    const float* __restrict__ t2, const float* __restrict__ t3,
    const float* __restrict__ t4,
    const float* __restrict__ gamma, const float* __restrict__ beta,
    const float* __restrict__ was4, const float* __restrict__ wad4,
    float* __restrict__ hout, float* __restrict__ a_s,
    float* __restrict__ a_d) {
  int b = blockIdx.x;
  if (b < COUNT_BLOCKS) {
    // scatter
    int i = b * 256 + threadIdx.x;
    int s, d;
    if (i < N_EDGES) { s = edge_index[i]; d = edge_index[N_EDGES + i]; }
    else if (i < TOT_EDGES) { s = i - N_EDGES; d = s; }
    else return;
    int pos = indptr[d] + atomicAdd(&cursor[d], 1);
    srcs[pos] = s;
    return;
  }
  // feats+LN+att1, wave-per-node (4 nodes / block, zero barriers).
  int lane = threadIdx.x & 63;
  int w = threadIdx.x >> 6;
  int n = (b - COUNT_BLOCKS) * 4 + w;
  if (n >= N_NODES) return;
  __shared__ int sidx[4][100];
  {
    int j = lane;                       // 0..63 -> tabs 0..3
    int tab = j / 20, l = j - tab * 20;
    const int* ip = tab == 0 ? i0 : tab == 1 ? i1 : tab == 2 ? i2 : i3;
    sidx[w][j] = ip[n * SEQ + l];
    if (lane < 36) {
      int j2 = 64 + lane;               // 64..99 -> tabs 3,4
      int tab2 = j2 / 20, l2 = j2 - tab2 * 20;
      const int* ip2 = tab2 == 3 ? i3 : i4;
      sidx[w][j2] = ip2[n * SEQ + l2];
    }
  }
  bool l48 = lane < 48;
  float f0, f1, f2 = 0.f;
  if (lane < SCALAR) {
    f0 = xs[n * SCALAR + lane];
  } else {
    int tt = lane - SCALAR, tab = tt >> 5, d = tt & 31;  // tab 0 or 1
    const float* tp = tab == 0 ? t0 : t1;
    float sum = 0.f, cnt = 0.f;
#pragma unroll
    for (int l = 0; l < SEQ; ++l) {
      int id = sidx[w][tab * 20 + l];
      if (id != 0) { sum += tp[id * EMB + d]; cnt += 1.f; }
    }
    f0 = sum / (cnt + 1e-9f);
  }
  {
    int tt = 48 + lane, tab = tt >> 5, d = tt & 31;      // tab 1,2,3
    const float* tp = tab == 1 ? t1 : tab == 2 ? t2 : t3;
    float sum = 0.f, cnt = 0.f;
#pragma unroll
    for (int l = 0; l < SEQ; ++l) {
      int id = sidx[w][tab * 20 + l];
      if (id != 0) { sum += tp[id * EMB + d]; cnt += 1.f; }
    }
    f1 = sum / (cnt + 1e-9f);
  }
  if (l48) {
    int tt = 112 + lane, tab = tt >> 5, d = tt & 31;     // tab 3 or 4
    const float* tp = tab == 3 ? t3 : t4;
    float sum = 0.f, cnt = 0.f;
#pragma unroll
    for (int l = 0; l < SEQ; ++l) {
      int id = sidx[w][tab * 20 + l];
      if (id != 0) { sum += tp[id * EMB + d]; cnt += 1.f; }
    }
    f2 = sum / (cnt + 1e-9f);
  }
  float s = f0 + f1 + f2;  // f2==0 for lane>=48
  for (int off = 1; off < 64; off <<= 1) s += __shfl_xor(s, off);
  float mu = s / (float)IN_DIM;
  float v = (f0 - mu) * (f0 - mu) + (f1 - mu) * (f1 - mu) +
            (l48 ? (f2 - mu) * (f2 - mu) : 0.f);
  for (int off = 1; off < 64; off <<= 1) v += __shfl_xor(v, off);
  float rstd = 1.0f / sqrtf(v / (float)IN_DIM + 1e-5f);
  float hv0 = (f0 - mu) * rstd * gamma[lane] + beta[lane];
  float hv1 = (f1 - mu) * rstd * gamma[64 + lane] + beta[64 + lane];
  float hv2 = l48 ? (f2 - mu) * rstd * gamma[128 + lane] + beta[128 + lane] : 0.f;
  float* hr = hout + (size_t)n * IN_DIM;
  hr[lane] = hv0;
  hr[64 + lane] = hv1;
  if (l48) hr[128 + lane] = hv2;

  // Fused layer-1 attention logits: ps/pd[h] = h_row . was/wad[:,h]
  const float4* wsv = (const float4*)was4;
  const float4* wdv = (const float4*)wad4;
  float4 wsa = wsv[lane], wsb = wsv[64 + lane];
  float4 wsc = l48 ? wsv[128 + lane] : make_float4(0.f, 0.f, 0.f, 0.f);
  float4 wda = wdv[lane], wdb = wdv[64 + lane];
  float4 wdc = l48 ? wdv[128 + lane] : make_float4(0.f, 0.f, 0.f, 0.f);
  float ps0 = hv0 * wsa.x + hv1 * wsb.x + hv2 * wsc.x;
  float ps1 = hv0 * wsa.y + hv1 * wsb.y + hv2 * wsc.y;
  float ps2 = hv0 * wsa.z + hv1 * wsb.z + hv2 * wsc.z;
  float ps3 = hv0 * wsa.w + hv1 * wsb.w + hv2 * wsc.w;
  float pd0 = hv0 * wda.x + hv1 * wdb.x + hv2 * wdc.x;
  float pd1 = hv0 * wda.y + hv1 * wdb.y + hv2 * wdc.y;
  float pd2 = hv0 * wda.z + hv1 * wdb.z + hv2 * wdc.z;
  float pd3 = hv0 * wda.w + hv1 * wdb.w + hv2 * wdc.w;
  for (int off = 1; off < 64; off <<= 1) {
    ps0 += __shfl_xor(ps0, off); ps1 += __shfl_xor(ps1, off);
    ps2 += __shfl_xor(ps2, off); ps3 += __shfl_xor(ps3, off);
    pd0 += __shfl_xor(pd0, off); pd1 += __shfl_xor(pd1, off);
    pd2 += __shfl_xor(pd2, off); pd3 += __shfl_xor(pd3, off);
  }
  if (lane == 0) {
    *(float4*)&a_s[n * 4] = make_float4(ps0, ps1, ps2, ps3);
    *(float4*)&a_d[n * 4] = make_float4(pd0, pd1, pd2, pd3);
  }
}

// ---------------------------------------------------------------------------
// Layer-1 softmax + aggregate h (176-dim) per head -> aggh[(ln*4+h)*176+k].
// (Aggregate in the SMALL dim first — round-5's GEMM-first variant tripled
// gather traffic, 318MB FETCH. Keep this order.)
// ---------------------------------------------------------------------------
__global__ __launch_bounds__(256) void agg1h_kernel(
    const float* __restrict__ h, const float* __restrict__ a_src,
    const float* __restrict__ a_dst, const int* __restrict__ indptr,
    const int* __restrict__ srcs, float* __restrict__ aggh,
    int n0, int nM) {
  int lane = threadIdx.x & 63;
  int ln = blockIdx.x * 4 + (threadIdx.x >> 6);
  if (ln >= nM) return;
  int n = n0 + ln;
  int beg = indptr[n], end = indptr[n + 1];
  int deg = end - beg;
  float4 ad = *(const float4*)&a_dst[n * 4];
  bool l48 = lane < 48;
  float acc[4][3] = {};

  auto body = [&](int s, float al0, float al1, float al2, float al3) {
    const float* r = h + (size_t)s * IN_DIM;
    float v0 = r[lane];
    float v1 = r[64 + lane];
    float v2 = l48 ? r[128 + lane] : 0.f;
    acc[0][0] += al0 * v0; acc[0][1] += al0 * v1; acc[0][2] += al0 * v2;
    acc[1][0] += al1 * v0; acc[1][1] += al1 * v1; acc[1][2] += al1 * v2;
    acc[2][0] += al2 * v0; acc[2][1] += al2 * v1; acc[2][2] += al2 * v2;
    acc[3][0] += al3 * v0; acc[3][1] += al3 * v1; acc[3][2] += al3 * v2;
  };

  if (deg <= 64) {
    int j = beg + lane;
    int s = 0;
    float e0 = -INFINITY, e1 = -INFINITY, e2 = -INFINITY, e3 = -INFINITY;
    if (j < end) {
      s = srcs[j];
      float4 as = *(const float4*)&a_src[s * 4];
      e0 = leaky(as.x + ad.x); e1 = leaky(as.y + ad.y);
      e2 = leaky(as.z + ad.z); e3 = leaky(as.w + ad.w);
    }
    float m0 = e0, m1 = e1, m2 = e2, m3 = e3;
    for (int off = 1; off < 64; off <<= 1) {
      m0 = fmaxf(m0, __shfl_xor(m0, off)); m1 = fmaxf(m1, __shfl_xor(m1, off));
      m2 = fmaxf(m2, __shfl_xor(m2, off)); m3 = fmaxf(m3, __shfl_xor(m3, off));
    }
    float x0 = (j < end) ? expf(e0 - m0) : 0.f;
    float x1 = (j < end) ? expf(e1 - m1) : 0.f;
    float x2 = (j < end) ? expf(e2 - m2) : 0.f;
    float x3 = (j < end) ? expf(e3 - m3) : 0.f;
    float d0 = x0, d1 = x1, d2 = x2, d3 = x3;
    for (int off = 1; off < 64; off <<= 1) {
      d0 += __shfl_xor(d0, off); d1 += __shfl_xor(d1, off);
      d2 += __shfl_xor(d2, off); d3 += __shfl_xor(d3, off);
    }
    float al0 = x0 / (d0 + 1e-16f), al1 = x1 / (d1 + 1e-16f);
    float al2 = x2 / (d2 + 1e-16f), al3 = x3 / (d3 + 1e-16f);
    int jj = 0;
    for (; jj + 2 <= deg; jj += 2) {
      int sa = readlane_i(s, jj), sb = readlane_i(s, jj + 1);
      float a0 = readlane_f(al0, jj), a1 = readlane_f(al1, jj);
      float a2 = readlane_f(al2, jj), a3 = readlane_f(al3, jj);
      float b0 = readlane_f(al0, jj + 1), b1 = readlane_f(al1, jj + 1);
      float b2 = readlane_f(al2, jj + 1), b3 = readlane_f(al3, jj + 1);
      body(sa, a0, a1, a2, a3);
      body(sb, b0, b1, b2, b3);
    }
    if (jj < deg) {
      int sa = readlane_i(s, jj);
      body(sa, readlane_f(al0, jj), readlane_f(al1, jj),
           readlane_f(al2, jj), readlane_f(al3, jj));
    }
  } else {
    float m0 = -INFINITY, m1 = -INFINITY, m2 = -INFINITY, m3 = -INFINITY;
    for (int j0 = beg; j0 < end; j0 += 64) {
      int j = j0 + lane;
      if (j < end) {
        int s = srcs[j];
        float4 as = *(const float4*)&a_src[s * 4];
        m0 = fmaxf(m0, leaky(as.x + ad.x)); m1 = fmaxf(m1, leaky(as.y + ad.y));
        m2 = fmaxf(m2, leaky(as.z + ad.z)); m3 = fmaxf(m3, leaky(as.w + ad.w));
      }
    }
    for (int off = 1; off < 64; off <<= 1) {
      m0 = fmaxf(m0, __shfl_xor(m0, off)); m1 = fmaxf(m1, __shfl_xor(m1, off));
      m2 = fmaxf(m2, __shfl_xor(m2, off)); m3 = fmaxf(m3, __shfl_xor(m3, off));
    }
    float d0 = 0.f, d1 = 0.f, d2 = 0.f, d3 = 0.f;
    for (int j0 = beg; j0 < end; j0 += 64) {
      int j = j0 + lane;
      if (j < end) {
        int s = srcs[j];
        float4 as = *(const float4*)&a_src[s * 4];
        d0 += expf(leaky(as.x + ad.x) - m0); d1 += expf(leaky(as.y + ad.y) - m1);
        d2 += expf(leaky(as.z + ad.z) - m2); d3 += expf(leaky(as.w + ad.w) - m3);
      }
    }
    for (int off = 1; off < 64; off <<= 1) {
      d0 += __shfl_xor(d0, off); d1 += __shfl_xor(d1, off);
      d2 += __shfl_xor(d2, off); d3 += __shfl_xor(d3, off);
    }
    float r0 = 1.f / (d0 + 1e-16f), r1 = 1.f / (d1 + 1e-16f);
    float r2 = 1.f / (d2 + 1e-16f), r3 = 1.f / (d3 + 1e-16f);
    for (int j0 = beg; j0 < end; j0 += 64) {
      int jn = min(64, end - j0);
      int j = j0 + lane;
      int s = 0;
      float al0 = 0.f, al1 = 0.f, al2 = 0.f, al3 = 0.f;
      if (j < end) {
        s = srcs[j];
        float4 as = *(const float4*)&a_src[s * 4];
        al0 = expf(leaky(as.x + ad.x) - m0) * r0;
        al1 = expf(leaky(as.y + ad.y) - m1) * r1;
        al2 = expf(leaky(as.z + ad.z) - m2) * r2;
        al3 = expf(leaky(as.w + ad.w) - m3) * r3;
      }
      for (int jj = 0; jj < jn; ++jj) {
        body(readlane_i(s, jj), readlane_f(al0, jj), readlane_f(al1, jj),
             readlane_f(al2, jj), readlane_f(al3, jj));
      }
    }
  }

  size_t base = (size_t)ln * (4 * IN_DIM);
#pragma unroll
  for (int hh = 0; hh < 4; ++hh) {
    aggh[base + hh * IN_DIM + lane] = acc[hh][0];
    aggh[base + hh * IN_DIM + 64 + lane] = acc[hh][1];
    if (l48) aggh[base + hh * IN_DIM + 128 + lane] = acc[hh][2];
  }
}

// ---------------------------------------------------------------------------
// Head-GEMM via f16 hi/lo MFMA (3-product fp32 emulation). LDS-free, no
// barriers. Wave tile 16 rows x 64 cols. wid = (rg*4+hh)*2+colhalf.
// K padded to 192: tail ks clamps A k-offset in-row; B zeros kill it.
// f32 stores (f16 stores inflated WRITE_SIZE 40->72MB in round 4).
// ---------------------------------------------------------------------------
__global__ __launch_bounds__(256) void gemm_head_mfma_kernel(
    const float* __restrict__ aggh, const half8v* __restrict__ PBh,
    const half8v* __restrict__ PBl, const float* __restrict__ b1,
    float* __restrict__ out1, int M, int n0) {
  int lane = threadIdx.x & 63;
  int wid = (blockIdx.x * 256 + threadIdx.x) >> 6;
  int colhalf = wid & 1;
  int hh = (wid >> 1) & 3;
  int rg = wid >> 3;
  int rows0 = rg * 16;
  if (rows0 >= M) return;
  int r = lane & 15, g = lane >> 4;
  f32x4 acc[4] = {};
  f32x4 accm[4] = {};
  const float* a0 = aggh + ((size_t)(rows0 + r) * 4 + hh) * IN_DIM;
#pragma unroll 2
  for (int ks = 0; ks < 6; ++ks) {
    int kg = ks * 32 + g * 8;
    int koff = (kg + 8 <= IN_DIM) ? kg : 0;  // clamp tail in-row (B zeros kill it)
    const float* ap = a0 + koff;
    float av[8];
    *(float4*)&av[0] = *(const float4*)(ap);
    *(float4*)&av[4] = *(const float4*)(ap + 4);
    half8v ah, al;
#pragma unroll
    for (int j = 0; j < 8; ++j) {
      _Float16 hv = (_Float16)av[j];
      ah[j] = hv;
      al[j] = (_Float16)((av[j] - (float)hv) * LO_SCALE);
    }
    const half8v* bh = PBh + (size_t)(((hh * 6 + ks) * 8 + colhalf * 4) * 64) + lane;
    const half8v* bl = PBl + (size_t)(((hh * 6 + ks) * 8 + colhalf * 4) * 64) + lane;
#pragma unroll
    for (int nt = 0; nt < 4; ++nt) {
      half8v bhv = bh[nt * 64], blv = bl[nt * 64];
      accm[nt] = __builtin_amdgcn_mfma_f32_16x16x32_f16(al, bhv, accm[nt], 0, 0, 0);
      accm[nt] = __builtin_amdgcn_mfma_f32_16x16x32_f16(ah, blv, accm[nt], 0, 0, 0);
      acc[nt]  = __builtin_amdgcn_mfma_f32_16x16x32_f16(ah, bhv, acc[nt], 0, 0, 0);
    }
  }
#pragma unroll
  for (int nt = 0; nt < 4; ++nt) {
    int col = hh * 128 + colhalf * 64 + nt * 16 + r;
    float bb = b1[col];
#pragma unroll
    for (int i = 0; i < 4; ++i) {
      int row = rows0 + g * 4 + i;
      if (row < M)
        out1[(size_t)(n0 + row) * 512 + col] =
            elu(acc[nt][i] + accm[nt][i] * LO_INV + bb);
    }
  }
}

// ---------------------------------------------------------------------------
// GEMM2 (out1@W2) via f16 hi/lo MFMA + fused layer-2 att logits.
// Wave tile 16 rows x 32 cols (5000 waves). wid = rg*4 + colq.
// ---------------------------------------------------------------------------
__global__ __launch_bounds__(256) void gemm2att_mfma_kernel(
    const float* __restrict__ A, const half8v* __restrict__ PBh,
    const half8v* __restrict__ PBl, const float* __restrict__ att_s,
    const float* __restrict__ att_d, float* __restrict__ C,
    float* __restrict__ a_s, float* __restrict__ a_d, int M) {
  int lane = threadIdx.x & 63;
  int wid = (blockIdx.x * 256 + threadIdx.x) >> 6;
  int colq = wid & 3;
  int rg = wid >> 2;
  int row0 = rg * 16;
  if (row0 >= M) return;
  int r = lane & 15, g = lane >> 4;
  const float* arow = A + (size_t)(row0 + r) * 512 + g * 8;
  f32x4 acc[2] = {};
  f32x4 accm[2] = {};
#pragma unroll 2
  for (int ks = 0; ks < 16; ++ks) {
    float av[8];
    *(float4*)&av[0] = *(const float4*)(arow + ks * 32);
    *(float4*)&av[4] = *(const float4*)(arow + ks * 32 + 4);
    half8v ah, al;
#pragma unroll
    for (int j = 0; j < 8; ++j) {
      _Float16 hv = (_Float16)av[j];
      ah[j] = hv;
      al[j] = (_Float16)((av[j] - (float)hv) * LO_SCALE);
    }
    const half8v* bh = PBh + (size_t)((ks * 8 + colq * 2) * 64) + lane;
    const half8v* bl = PBl + (size_t)((ks * 8 + colq * 2) * 64) + lane;
#pragma unroll
    for (int nt = 0; nt < 2; ++nt) {
      half8v bhv = bh[nt * 64], blv = bl[nt * 64];
      accm[nt] = __builtin_amdgcn_mfma_f32_16x16x32_f16(al, bhv, accm[nt], 0, 0, 0);
      accm[nt] = __builtin_amdgcn_mfma_f32_16x16x32_f16(ah, blv, accm[nt], 0, 0, 0);
      acc[nt]  = __builtin_amdgcn_mfma_f32_16x16x32_f16(ah, bhv, acc[nt], 0, 0, 0);
    }
  }
  float ps[4] = {0.f, 0.f, 0.f, 0.f}, pd[4] = {0.f, 0.f, 0.f, 0.f};
#pragma unroll
  for (int nt = 0; nt < 2; ++nt) {
    int col = colq * 32 + nt * 16 + r;
    float as_ = att_s[col], ad_ = att_d[col];
#pragma unroll
    for (int i = 0; i < 4; ++i) {
      float v = acc[nt][i] + accm[nt][i] * LO_INV;
      int row = row0 + g * 4 + i;
      C[(size_t)row * 128 + col] = v;
      ps[i] += v * as_;
      pd[i] += v * ad_;
    }
  }
#pragma unroll
  for (int i = 0; i < 4; ++i) {
    for (int off = 1; off < 16; off <<= 1) {
      ps[i] += __shfl_xor(ps[i], off);
      pd[i] += __shfl_xor(pd[i], off);
    }
  }
  if (r == 0) {
#pragma unroll
    for (int i = 0; i < 4; ++i) {
      atomicAdd(&a_s[row0 + g * 4 + i], ps[i]);
      atomicAdd(&a_d[row0 + g * 4 + i], pd[i]);
    }
  }
}

// ---------------------------------------------------------------------------
// Layer-2 aggregate: H=1, C=128. Half-wave per edge, float4 loads.
// ---------------------------------------------------------------------------
__global__ __launch_bounds__(256) void agg2_kernel(
    const float* __restrict__ xw, const float* __restrict__ a_src,
    const float* __restrict__ a_dst, const int* __restrict__ indptr,
    const int* __restrict__ srcs, const float* __restrict__ bias,
    float* __restrict__ out) {
  int lane = threadIdx.x & 63;
  int n = blockIdx.x * 4 + (threadIdx.x >> 6);
  if (n >= N_NODES) return;
  int beg = indptr[n], end = indptr[n + 1];
  int deg = end - beg;
  float adn = a_dst[n];
  int half = lane >> 5, l32 = lane & 31;
  float4 acc = make_float4(0.f, 0.f, 0.f, 0.f);

  auto pairs = [&](int s, float al, int jn) {
    int jj = 0;
    for (; jj + 2 <= jn; jj += 2) {
      int sa = readlane_i(s, jj), sb = readlane_i(s, jj + 1);
      float aa = readlane_f(al, jj), ab = readlane_f(al, jj + 1);
      int sh = half ? sb : sa;
      float ahx = half ? ab : aa;
      float4 v = *(const float4*)&xw[(size_t)sh * HID + l32 * 4];
      acc.x += ahx * v.x; acc.y += ahx * v.y; acc.z += ahx * v.z; acc.w += ahx * v.w;
    }
    if (jj < jn) {
      int sa = readlane_i(s, jj);
      float ahx = half ? 0.f : readlane_f(al, jj);
      float4 v = *(const float4*)&xw[(size_t)sa * HID + l32 * 4];
      acc.x += ahx * v.x; acc.y += ahx * v.y; acc.z += ahx * v.z; acc.w += ahx * v.w;
    }
  };

  if (deg <= 64) {
    int j = beg + lane;
    int s = 0;
    float e = -INFINITY;
    if (j < end) { s = srcs[j]; e = leaky(a_src[s] + adn); }
    float m = e;
    for (int off = 1; off < 64; off <<= 1) m = fmaxf(m, __shfl_xor(m, off));
    float x = (j < end) ? expf(e - m) : 0.f;
    float d = x;
    for (int off = 1; off < 64; off <<= 1) d += __shfl_xor(d, off);
    float al = x / (d + 1e-16f);
    pairs(s, al, deg);
  } else {
    float m = -INFINITY;
    for (int j0 = beg; j0 < end; j0 += 64) {
      int j = j0 + lane;
      if (j < end) m = fmaxf(m, leaky(a_src[srcs[j]] + adn));
    }
    for (int off = 1; off < 64; off <<= 1) m = fmaxf(m, __shfl_xor(m, off));
    float d = 0.f;
    for (int j0 = beg; j0 < end; j0 += 64) {
      int j = j0 + lane;
      if (j < end) d += expf(leaky(a_src[srcs[j]] + adn) - m);
    }
    for (int off = 1; off < 64; off <<= 1) d += __shfl_xor(d, off);
    float rd = 1.f / (d + 1e-16f);
    for (int j0 = beg; j0 < end; j0 += 64) {
      int jn = min(64, end - j0);
      int j = j0 + lane;
      int s = 0;
      float al = 0.f;
      if (j < end) {
        s = srcs[j];
        al = expf(leaky(a_src[s] + adn) - m) * rd;
      }
      pairs(s, al, jn);
    }
  }

  acc.x += __shfl_xor(acc.x, 32); acc.y += __shfl_xor(acc.y, 32);
  acc.z += __shfl_xor(acc.z, 32); acc.w += __shfl_xor(acc.w, 32);
  if (half == 0) {
    float4 b = *(const float4*)&bias[l32 * 4];
    float4 o;
    o.x = elu(acc.x + b.x); o.y = elu(acc.y + b.y);
    o.z = elu(acc.z + b.z); o.w = elu(acc.w + b.w);
    *(float4*)&out[(size_t)n * HID + l32 * 4] = o;
  }
}

// ---------------------------------------------------------------------------
// Two-stage max-pool per graph, classifier head.
// ---------------------------------------------------------------------------
__global__ __launch_bounds__(HID) void pool_part_kernel(
    const float* __restrict__ out2, const int* __restrict__ gstarts,
    float* __restrict__ part) {
  int g = blockIdx.x, s = blockIdx.y, t = threadIdx.x;
  int beg = gstarts[g], end = gstarts[g + 1];
  int len = end - beg;
  int b0 = beg + (int)(((long long)len * s) / POOL_SLICES);
  int b1 = beg + (int)(((long long)len * (s + 1)) / POOL_SLICES);
  float m = -INFINITY;
  for (int n = b0; n < b1; ++n) m = fmaxf(m, out2[(size_t)n * HID + t]);
  part[((size_t)g * POOL_SLICES + s) * HID + t] = m;
}

__global__ __launch_bounds__(HID) void pool_reduce_kernel(
    const float* __restrict__ part, float* __restrict__ pooled) {
  int g = blockIdx.x, t = threadIdx.x;
  float m = -INFINITY;
#pragma unroll
  for (int s = 0; s < POOL_SLICES; ++s)
    m = fmaxf(m, part[((size_t)g * POOL_SLICES + s) * HID + t]);
  pooled[g * HID + t] = m;
}

__global__ __launch_bounds__(HID) void cls_kernel(const float* __restrict__ pooled,
                                                  const float* __restrict__ w1,
                                                  const float* __restrict__ b1,
                                                  const float* __restrict__ w2,
                                                  const float* __restrict__ b2,
                                                  float* __restrict__ out) {
  int g = blockIdx.x, t = threadIdx.x;
  __shared__ float sp[HID], sh1[HID / 2];
  sp[t] = pooled[g * HID + t];
  __syncthreads();
  if (t < HID / 2) {
    float s = b1[t];
    for (int k = 0; k < HID; ++k) s += sp[k] * w1[k * (HID / 2) + t];
    sh1[t] = fmaxf(s, 0.f);
  }
  __syncthreads();
  if (t < 2) {
    float o = b2[t];
    for (int k = 0; k < HID / 2; ++k) o += sh1[k] * w2[k * 2 + t];
    out[g * 2 + t] = o;
  }
}

// ---------------------------------------------------------------------------
extern "C" void kernel_launch(void* const* d_in, const int* in_sizes, int n_in,
                              void* d_out, int out_size, void* d_ws, size_t ws_size,
                              hipStream_t stream) {
  const float* x_scalar = (const float*)d_in[0];
  const int* x_opcode   = (const int*)d_in[1];
  const int* x_source   = (const int*)d_in[2];
  const int* x_sink     = (const int*)d_in[3];
  const int* x_string   = (const int*)d_in[4];
  const int* x_payload  = (const int*)d_in[5];
  const int* edge_index = (const int*)d_in[6];
  const int* batch      = (const int*)d_in[7];
  const float* emb_opcode = (const float*)d_in[8];
  const float* emb_source = (const float*)d_in[9];
  const float* emb_sink   = (const float*)d_in[10];
  const float* emb_string = (const float*)d_in[11];
  const float* emb_payload= (const float*)d_in[12];
  const float* ln_gamma = (const float*)d_in[13];
  const float* ln_beta  = (const float*)d_in[14];
  const float* W1       = (const float*)d_in[15];
  const float* att_src1 = (const float*)d_in[16];
  const float* att_dst1 = (const float*)d_in[17];
  const float* b1       = (const float*)d_in[18];
  const float* W2       = (const float*)d_in[19];
  const float* att_src2 = (const float*)d_in[20];
  const float* att_dst2 = (const float*)d_in[21];
  const float* b2       = (const float*)d_in[22];
  const float* cls_w1   = (const float*)d_in[23];
  const float* cls_b1   = (const float*)d_in[24];
  const float* cls_w2   = (const float*)d_in[25];
  const float* cls_b2   = (const float*)d_in[26];

  // Adaptive chunk: run layer-1 agg + head-GEMM in 1 pass if workspace allows.
  auto total_bytes = [&](int chunk) -> size_t {
    size_t f = (size_t)N_NODES * IN_DIM + (size_t)chunk * 4 * IN_DIM +
               (size_t)N_NODES * 512 + (size_t)N_NODES * HID +
               N_NODES * 4 * 2 + N_NODES * 2 + IN_DIM * 4 * 2 + N_GRAPHS * HID;
    size_t ii = (N_NODES + 1) + N_NODES * 2 + TOT_EDGES + (N_GRAPHS + 1);
    size_t f16b = (size_t)2 * (PB2_ELEMS + PB1_ELEMS) * sizeof(_Float16) + 32;
    size_t poolb = (size_t)N_GRAPHS * POOL_SLICES * HID * 4 + 32;
    return f * 4 + ii * 4 + f16b + poolb + 256;
  };
  int chunk = (ws_size >= total_bytes(N_NODES)) ? N_NODES : CHUNK_SMALL;

  float* h      = (float*)d_ws;                        // [N,176]
  float* aggh   = h + (size_t)N_NODES * IN_DIM;        // [chunk*704]
  float* out1   = aggh + (size_t)chunk * 4 * IN_DIM;   // [N,512]
  float* out2   = out1 + (size_t)N_NODES * 512;        // [N,128]
  float* a1s    = out2 + (size_t)N_NODES * HID;        // [N,4]
  float* a1d    = a1s + N_NODES * 4;
  float* was4   = a1d + N_NODES * 4;                   // [176*4]
  float* wad4   = was4 + IN_DIM * 4;                   // [176*4]
  float* pooled = wad4 + IN_DIM * 4;                   // [G,128]
  int* indptr = (int*)(pooled + N_GRAPHS * HID);       // [N+1]
  int* cnt    = indptr + (N_NODES + 1);                // [N]   (zeroed)
  int* cursor = cnt + N_NODES;                         // [N]   (zeroed)
  float* a2s  = (float*)(cursor + N_NODES);            // [N]   (zeroed)
  float* a2d  = a2s + N_NODES;                         // [N]   (zeroed)
  int* srcs   = (int*)(a2d + N_NODES);                 // [E+N]
  int* gstarts= srcs + TOT_EDGES;                      // [G+1]
  // f16 pack buffers, 16B-aligned (half8v loads)
  uintptr_t pal = ((uintptr_t)(gstarts + N_GRAPHS + 1) + 15) & ~(uintptr_t)15;
  _Float16* PB2h = (_Float16*)pal;                     // [65536]
  _Float16* PB2l = PB2h + PB2_ELEMS;                   // [65536]
  _Float16* PB1h = PB2l + PB2_ELEMS;                   // [98304]
  _Float16* PB1l = PB1h + PB1_ELEMS;                   // [98304]
  uintptr_t ppal = ((uintptr_t)(PB1l + PB1_ELEMS) + 15) & ~(uintptr_t)15;
  float* pool_part = (float*)ppal;                     // [G*32*128]
  float* xw2  = h;  // alias: h dead after last agg1h; xw2 [N,128] fits in h [N,176]

  // zero cnt, cursor, a2s, a2d in one shot (contiguous)
  hipMemsetAsync(cnt, 0, 4 * N_NODES * sizeof(int), stream);

  // LAUNCH 1: setup (wasd+pack) || CSR count || gstart — all input-only.
  setup_count_kernel<<<SETUP_BLOCKS + COUNT_BLOCKS + 1, 256, 0, stream>>>(
      W1, att_src1, att_dst1, W2, edge_index, batch,
      was4, wad4, PB1h, PB1l, PB2h, PB2l, cnt, gstarts);

  // LAUNCH 2: prefix scan (needs count).
  prefix_kernel<<<1, 1024, 0, stream>>>(cnt, indptr, N_NODES, TOT_EDGES);

  // LAUNCH 3: scatter (needs prefix) || feats+LN+att1 (needs setup).
  scatter_feats_kernel<<<COUNT_BLOCKS + NB4, 256, 0, stream>>>(
      edge_index, indptr, cursor, srcs,
      x_scalar, x_opcode, x_source, x_sink, x_string, x_payload,
      emb_opcode, emb_source, emb_sink, emb_string, emb_payload,
      ln_gamma, ln_beta, was4, wad4, h, a1s, a1d);

  for (int n0 = 0; n0 < N_NODES; n0 += chunk) {
    int nM = min(chunk, N_NODES - n0);
    agg1h_kernel<<<(nM + 3) / 4, 256, 0, stream>>>(h, a1s, a1d, indptr, srcs, aggh, n0, nM);
    int rgs = (nM + 15) / 16;           // 16 rows per wave
    gemm_head_mfma_kernel<<<rgs * 2, 256, 0, stream>>>(   // rgs*8 waves / 4 per block
        aggh, (const half8v*)PB1h, (const half8v*)PB1l, b1, out1, nM, n0);
  }

  // GEMM2 + fused att2 logits via MFMA: 5000 waves = 1250 blocks.
  gemm2att_mfma_kernel<<<(N_NODES + 15) / 16, 256, 0, stream>>>(
      out1, (const half8v*)PB2h, (const half8v*)PB2l, att_src2, att_dst2,
      xw2, a2s, a2d, N_NODES);

  agg2_kernel<<<NB4, 256, 0, stream>>>(xw2, a2s, a2d, indptr, srcs, b2, out2);

  pool_part_kernel<<<dim3(N_GRAPHS, POOL_SLICES), HID, 0, stream>>>(out2, gstarts, pool_part);
  pool_reduce_kernel<<<N_GRAPHS, HID, 0, stream>>>(pool_part, pooled);
  cls_kernel<<<N_GRAPHS, HID, 0, stream>>>(pooled, cls_w1, cls_b1, cls_w2, cls_b2, (float*)d_out);
}